// Round 4
// baseline (401.791 us; speedup 1.0000x reference)
//
#include <hip/hip_runtime.h>
#include <hip/hip_bf16.h>

using bf16 = __hip_bfloat16;
typedef __attribute__((ext_vector_type(8))) short short8;
typedef __attribute__((ext_vector_type(4))) float f32x4;

#define ZN 4096
#define KN 48

__device__ __forceinline__ float gelu_f(float x) {
    return 0.5f * x * (1.0f + erff(x * 0.70710678118654752440f));
}

__device__ __forceinline__ uint2 pack4(float a, float b, float c, float d) {
    union { bf16 h[4]; uint2 u; } t;
    t.h[0] = __float2bfloat16(a); t.h[1] = __float2bfloat16(b);
    t.h[2] = __float2bfloat16(c); t.h[3] = __float2bfloat16(d);
    return t.u;
}

// Pack W[K][128] (row-major f32) into bf16 MFMA B-fragment order:
// P[((ks*8 + nt)*64 + lane)*8 + j] = bf16(W[ks*32 + (lane>>4)*8 + j][nt*16 + (lane&15)])
__global__ void pack_b_kernel(const float* __restrict__ W, bf16* __restrict__ P, int total) {
    int idx = blockIdx.x * 256 + threadIdx.x;
    if (idx >= total) return;
    int j    = idx & 7;
    int lane = (idx >> 3) & 63;
    int nt   = (idx >> 9) & 7;
    int ks   = idx >> 12;
    int k = ks * 32 + ((lane >> 4) << 3) + j;
    int n = nt * 16 + (lane & 15);
    P[idx] = __float2bfloat16(W[k * 128 + n]);
}

// One GEMM stage: A [48][ldA] bf16 in LDS, B packed bf16, 3 M-tiles x 2 N-tiles per wave.
template<int KSBEG, int NSTEPS>
__device__ __forceinline__ void do_gemm(const bf16* A, int ldA, const bf16* Bp,
                                        int lane, int nt0, f32x4 acc[3][2]) {
    #pragma unroll
    for (int s = 0; s < NSTEPS; ++s) {
        int ks = KSBEG + s;
        short8 b0 = *(const short8*)(Bp + (((ks * 8 + nt0) * 64 + lane) << 3));
        short8 b1 = *(const short8*)(Bp + (((ks * 8 + nt0 + 1) * 64 + lane) << 3));
        int kcol = s * 32 + ((lane >> 4) << 3);
        #pragma unroll
        for (int mt = 0; mt < 3; ++mt) {
            short8 a = *(const short8*)(A + (mt * 16 + (lane & 15)) * ldA + kcol);
            acc[mt][0] = __builtin_amdgcn_mfma_f32_16x16x32_bf16(a, b0, acc[mt][0], 0, 0, 0);
            acc[mt][1] = __builtin_amdgcn_mfma_f32_16x16x32_bf16(a, b1, acc[mt][1], 0, 0, 0);
        }
    }
}

template<bool NODE_PASS>
__global__ __launch_bounds__(256, 2)
void msg_kernel(const float* __restrict__ Vf,     // Vj gather source (f32): V (node) or V2 (edge)
                const float* __restrict__ ViF,    // Vi source (f32): V (node) or V2 (edge)
                const float* __restrict__ Ef,     // E (f32)
                const float* __restrict__ maskf,
                const int*   __restrict__ Kidx,
                const float* __restrict__ w1raw,  // [384][128] f32 (rows 0..127 = Vi part)
                const bf16* __restrict__ w1p, const float* __restrict__ b1f,
                const bf16* __restrict__ w2p, const float* __restrict__ b2f,
                const bf16* __restrict__ w3p, const float* __restrict__ b3f,
                const float* __restrict__ lng, const float* __restrict__ lnb,
                const float* __restrict__ Vres,   // node pass residual (f32 V)
                float* __restrict__ V1out,        // node pass output (f32, ws)
                float* __restrict__ Eout)         // edge pass output (f32, d_out)
{
    __shared__ __align__(16) char region0[48 * 138 * 4];   // sA (bf16[48][264]) / sMe (f32[48][138])
    __shared__ __align__(16) bf16 sH1[48][136];
    __shared__ __align__(16) bf16 sH2[48][136];
    __shared__ float sVi[128];
    __shared__ float sYvi[128];
    __shared__ float sMask[48];
    __shared__ float sS[128];

    bf16  (*sA)[264]  = reinterpret_cast<bf16(*)[264]>(region0);
    float (*sMe)[138] = reinterpret_cast<float(*)[138]>(region0);

    const int node = blockIdx.x;
    const int tid  = threadIdx.x;
    const int lane = tid & 63;
    const int wid  = tid >> 6;
    const int z    = node >> 10;
    const int* krow = Kidx + node * KN;

    // ---- stage Vi (f32), mask, and A rows [Vj | E] (bf16) ----
    if (tid < 128) sVi[tid] = ViF[(size_t)node * 128 + tid];
    if (tid >= 128 && tid < 128 + KN)
        sMask[tid - 128] = maskf[(size_t)node * KN + (tid - 128)];
    {
        const float* erow0 = Ef + (size_t)node * KN * 128;
        for (int c = tid; c < KN * 32; c += 256) {
            int r = c >> 5;
            int off = (c & 31) * 4;
            int kj = krow[r];
            float4 vj = *(const float4*)(Vf + ((size_t)(z * 1024 + kj)) * 128 + off);
            *(uint2*)&sA[r][off] = pack4(vj.x, vj.y, vj.z, vj.w);
            float4 ee = *(const float4*)(erow0 + r * 128 + off);
            *(uint2*)&sA[r][128 + off] = pack4(ee.x, ee.y, ee.z, ee.w);
        }
    }
    __syncthreads();

    // ---- y_vi = b1 + Vi @ w1[0:128,:]  (identical for all 48 rows, f32) ----
    if (tid < 128) {
        float acc = b1f[tid];
        #pragma unroll 4
        for (int i = 0; i < 128; ++i)
            acc += sVi[i] * w1raw[i * 128 + tid];
        sYvi[tid] = acc;
    }
    __syncthreads();

    const int nt0 = wid * 2;
    const int lm  = lane & 15;
    const int lg  = lane >> 4;
    const f32x4 vzero = {0.f, 0.f, 0.f, 0.f};

    // ---- GEMM1: [48][256](Vj|E) @ w1[128:384][:] ----
    f32x4 acc[3][2];
    #pragma unroll
    for (int mt = 0; mt < 3; ++mt) { acc[mt][0] = vzero; acc[mt][1] = vzero; }
    do_gemm<4, 8>(&sA[0][0], 264, w1p, lane, nt0, acc);
    #pragma unroll
    for (int mt = 0; mt < 3; ++mt)
    #pragma unroll
    for (int ni = 0; ni < 2; ++ni) {
        int col = (nt0 + ni) * 16 + lm;
        float yv = sYvi[col];
        #pragma unroll
        for (int r = 0; r < 4; ++r) {
            int row = mt * 16 + lg * 4 + r;
            sH1[row][col] = __float2bfloat16(gelu_f(acc[mt][ni][r] + yv));
        }
    }
    __syncthreads();

    // ---- GEMM2: H1 @ w2 ----
    #pragma unroll
    for (int mt = 0; mt < 3; ++mt) { acc[mt][0] = vzero; acc[mt][1] = vzero; }
    do_gemm<0, 4>(&sH1[0][0], 136, w2p, lane, nt0, acc);
    {
        float bc0 = b2f[nt0 * 16 + lm];
        float bc1 = b2f[(nt0 + 1) * 16 + lm];
        #pragma unroll
        for (int mt = 0; mt < 3; ++mt)
        #pragma unroll
        for (int r = 0; r < 4; ++r) {
            int row = mt * 16 + lg * 4 + r;
            sH2[row][nt0 * 16 + lm]       = __float2bfloat16(gelu_f(acc[mt][0][r] + bc0));
            sH2[row][(nt0 + 1) * 16 + lm] = __float2bfloat16(gelu_f(acc[mt][1][r] + bc1));
        }
    }
    __syncthreads();

    // ---- GEMM3: H2 @ w3, + b3, * mask ----
    #pragma unroll
    for (int mt = 0; mt < 3; ++mt) { acc[mt][0] = vzero; acc[mt][1] = vzero; }
    do_gemm<0, 4>(&sH2[0][0], 136, w3p, lane, nt0, acc);
    {
        float bc0 = b3f[nt0 * 16 + lm];
        float bc1 = b3f[(nt0 + 1) * 16 + lm];
        if (NODE_PASS) {
            float cs0 = 0.f, cs1 = 0.f;
            #pragma unroll
            for (int mt = 0; mt < 3; ++mt)
            #pragma unroll
            for (int r = 0; r < 4; ++r) {
                float m = sMask[mt * 16 + lg * 4 + r];
                cs0 += (acc[mt][0][r] + bc0) * m;
                cs1 += (acc[mt][1][r] + bc1) * m;
            }
            cs0 += __shfl_xor(cs0, 16); cs0 += __shfl_xor(cs0, 32);
            cs1 += __shfl_xor(cs1, 16); cs1 += __shfl_xor(cs1, 32);
            if (lane < 16) {
                sS[nt0 * 16 + lane]       = cs0;
                sS[(nt0 + 1) * 16 + lane] = cs1;
            }
        } else {
            #pragma unroll
            for (int mt = 0; mt < 3; ++mt)
            #pragma unroll
            for (int r = 0; r < 4; ++r) {
                int row = mt * 16 + lg * 4 + r;
                float m = sMask[row];
                sMe[row][nt0 * 16 + lm]       = (acc[mt][0][r] + bc0) * m;
                sMe[row][(nt0 + 1) * 16 + lm] = (acc[mt][1][r] + bc1) * m;
            }
        }
    }
    __syncthreads();

    // ---- finalize ----
    if (NODE_PASS) {
        if (tid < 64) {
            float a = Vres[(size_t)node * 128 + tid]      + sS[tid];
            float b = Vres[(size_t)node * 128 + tid + 64] + sS[tid + 64];
            float s = a + b, q = a * a + b * b;
            #pragma unroll
            for (int off = 32; off; off >>= 1) { s += __shfl_xor(s, off); q += __shfl_xor(q, off); }
            float mean = s * (1.f / 128.f);
            float var  = q * (1.f / 128.f) - mean * mean;
            float rs   = rsqrtf(var + 1e-5f);
            V1out[(size_t)node * 128 + tid]      = (a - mean) * rs * lng[tid]      + lnb[tid];
            V1out[(size_t)node * 128 + tid + 64] = (b - mean) * rs * lng[tid + 64] + lnb[tid + 64];
        }
    } else {
        for (int r = wid; r < KN; r += 4) {
            float2 ev = ((const float2*)(Ef + ((size_t)node * KN + r) * 128))[lane];
            float x0 = ev.x + sMe[r][2 * lane];
            float x1 = ev.y + sMe[r][2 * lane + 1];
            float s = x0 + x1, q = x0 * x0 + x1 * x1;
            #pragma unroll
            for (int off = 32; off; off >>= 1) { s += __shfl_xor(s, off); q += __shfl_xor(q, off); }
            float mean = s * (1.f / 128.f);
            float var  = q * (1.f / 128.f) - mean * mean;
            float rs   = rsqrtf(var + 1e-5f);
            float2 o;
            o.x = (x0 - mean) * rs * lng[2 * lane]     + lnb[2 * lane];
            o.y = (x1 - mean) * rs * lng[2 * lane + 1] + lnb[2 * lane + 1];
            ((float2*)(Eout + ((size_t)node * KN + r) * 128))[lane] = o;
        }
    }
}

// FFN: V2 = LN(V1 + gelu(V1@w1+b1)@w2+b2), 16 nodes per block (VALU, f32).
__global__ __launch_bounds__(256, 2)
void ffn_kernel(const float* __restrict__ V1,
                const float* __restrict__ w1, const float* __restrict__ b1,   // [128][512], [512]
                const float* __restrict__ w2, const float* __restrict__ b2,   // [512][128], [128]
                const float* __restrict__ g, const float* __restrict__ bta,
                float* __restrict__ Vout)
{
    constexpr int NODES = 16;
    __shared__ float sV[NODES][128];
    __shared__ float sH[NODES][512];
    __shared__ float sX[NODES][128];

    const int nb  = blockIdx.x * NODES;
    const int tid = threadIdx.x;

    for (int i = tid; i < NODES * 128; i += 256)
        sV[i >> 7][i & 127] = V1[(size_t)nb * 128 + i];
    __syncthreads();

    #pragma unroll
    for (int jj = 0; jj < 2; ++jj) {
        int j = tid + jj * 256;
        float acc[NODES];
        float bj = b1[j];
        #pragma unroll
        for (int n = 0; n < NODES; ++n) acc[n] = bj;
        for (int i = 0; i < 128; ++i) {
            float wv = w1[i * 512 + j];
            #pragma unroll
            for (int n = 0; n < NODES; ++n) acc[n] += sV[n][i] * wv;
        }
        #pragma unroll
        for (int n = 0; n < NODES; ++n) sH[n][j] = gelu_f(acc[n]);
    }
    __syncthreads();

    {
        int d  = tid & 127;
        int n0 = (tid >> 7) * 8;
        float acc[8];
        float bd = b2[d];
        #pragma unroll
        for (int u = 0; u < 8; ++u) acc[u] = bd;
        for (int j = 0; j < 512; ++j) {
            float wv = w2[j * 128 + d];
            #pragma unroll
            for (int u = 0; u < 8; ++u) acc[u] += sH[n0 + u][j] * wv;
        }
        #pragma unroll
        for (int u = 0; u < 8; ++u) sX[n0 + u][d] = sV[n0 + u][d] + acc[u];
    }
    __syncthreads();

    const int wid = tid >> 6, lane = tid & 63;
    for (int n = wid; n < NODES; n += 4) {
        float a = sX[n][lane], b = sX[n][lane + 64];
        float s = a + b, q = a * a + b * b;
        #pragma unroll
        for (int off = 32; off; off >>= 1) { s += __shfl_xor(s, off); q += __shfl_xor(q, off); }
        float mean = s * (1.f / 128.f);
        float var  = q * (1.f / 128.f) - mean * mean;
        float rs   = rsqrtf(var + 1e-5f);
        size_t base = (size_t)(nb + n) * 128;
        Vout[base + lane]      = (a - mean) * rs * g[lane]      + bta[lane];
        Vout[base + lane + 64] = (b - mean) * rs * g[lane + 64] + bta[lane + 64];
    }
}

extern "C" void kernel_launch(void* const* d_in, const int* in_sizes, int n_in,
                              void* d_out, int out_size, void* d_ws, size_t ws_size,
                              hipStream_t stream) {
    const float* V     = (const float*)d_in[0];
    const float* E     = (const float*)d_in[1];
    const float* emask = (const float*)d_in[2];
    const float* nm_w1 = (const float*)d_in[3];
    const float* nm_b1 = (const float*)d_in[4];
    const float* nm_w2 = (const float*)d_in[5];
    const float* nm_b2 = (const float*)d_in[6];
    const float* nm_w3 = (const float*)d_in[7];
    const float* nm_b3 = (const float*)d_in[8];
    const float* nmn_g = (const float*)d_in[9];
    const float* nmn_b = (const float*)d_in[10];
    const float* ffn_w1 = (const float*)d_in[11];
    const float* ffn_b1 = (const float*)d_in[12];
    const float* ffn_w2 = (const float*)d_in[13];
    const float* ffn_b2 = (const float*)d_in[14];
    const float* fn_g  = (const float*)d_in[15];
    const float* fn_b  = (const float*)d_in[16];
    const float* em_w1 = (const float*)d_in[17];
    const float* em_b1 = (const float*)d_in[18];
    const float* em_w2 = (const float*)d_in[19];
    const float* em_b2 = (const float*)d_in[20];
    const float* em_w3 = (const float*)d_in[21];
    const float* em_b3 = (const float*)d_in[22];
    const float* emn_g = (const float*)d_in[23];
    const float* emn_b = (const float*)d_in[24];
    const int*  K     = (const int*)d_in[25];

    char* ws = (char*)d_ws;
    bf16* p_nm_w1 = (bf16*)(ws);
    bf16* p_nm_w2 = (bf16*)(ws + 98304);
    bf16* p_nm_w3 = (bf16*)(ws + 131072);
    bf16* p_em_w1 = (bf16*)(ws + 163840);
    bf16* p_em_w2 = (bf16*)(ws + 262144);
    bf16* p_em_w3 = (bf16*)(ws + 294912);
    float* V1f = (float*)(ws + 327680);

    float* V2out = (float*)d_out;                 // [4,1024,128] f32
    float* Eout  = (float*)d_out + 524288;        // [4,1024,48,128] f32

    pack_b_kernel<<<192, 256, 0, stream>>>(nm_w1, p_nm_w1, 49152);
    pack_b_kernel<<<64,  256, 0, stream>>>(nm_w2, p_nm_w2, 16384);
    pack_b_kernel<<<64,  256, 0, stream>>>(nm_w3, p_nm_w3, 16384);
    pack_b_kernel<<<192, 256, 0, stream>>>(em_w1, p_em_w1, 49152);
    pack_b_kernel<<<64,  256, 0, stream>>>(em_w2, p_em_w2, 16384);
    pack_b_kernel<<<64,  256, 0, stream>>>(em_w3, p_em_w3, 16384);

    msg_kernel<true><<<ZN, 256, 0, stream>>>(
        V, V, E, emask, K,
        nm_w1, p_nm_w1, nm_b1, p_nm_w2, nm_b2, p_nm_w3, nm_b3,
        nmn_g, nmn_b, V, V1f, nullptr);

    ffn_kernel<<<ZN / 16, 256, 0, stream>>>(
        V1f, ffn_w1, ffn_b1, ffn_w2, ffn_b2, fn_g, fn_b, V2out);

    msg_kernel<false><<<ZN, 256, 0, stream>>>(
        V2out, V2out, E, emask, K,
        em_w1, p_em_w1, em_b1, p_em_w2, em_b2, p_em_w3, em_b3,
        emn_g, emn_b, nullptr, nullptr, Eout);
}

// Round 9
// 347.582 us; speedup vs baseline: 1.1560x; 1.1560x over previous
//
#include <hip/hip_runtime.h>
#include <hip/hip_bf16.h>

using bf16 = __hip_bfloat16;
typedef __attribute__((ext_vector_type(8))) short short8;
typedef __attribute__((ext_vector_type(4))) float f32x4;

#define ZN 4096
#define KN 48

__device__ __forceinline__ float gelu_f(float x) {
    return 0.5f * x * (1.0f + erff(x * 0.70710678118654752440f));
}

__device__ __forceinline__ uint2 pack4(float a, float b, float c, float d) {
    union { bf16 h[4]; uint2 u; } t;
    t.h[0] = __float2bfloat16(a); t.h[1] = __float2bfloat16(b);
    t.h[2] = __float2bfloat16(c); t.h[3] = __float2bfloat16(d);
    return t.u;
}

// Pack W[K][128] (row-major f32) into bf16 MFMA B-fragment order (round-4 verbatim):
// P[((ks*8 + nt)*64 + lane)*8 + j] = bf16(W[ks*32 + (lane>>4)*8 + j][nt*16 + (lane&15)])
__global__ void pack_b_kernel(const float* __restrict__ W, bf16* __restrict__ P, int total) {
    int idx = blockIdx.x * 256 + threadIdx.x;
    if (idx >= total) return;
    int j    = idx & 7;
    int lane = (idx >> 3) & 63;
    int nt   = (idx >> 9) & 7;
    int ks   = idx >> 12;
    int k = ks * 32 + ((lane >> 4) << 3) + j;
    int n = nt * 16 + (lane & 15);
    P[idx] = __float2bfloat16(W[k * 128 + n]);
}

// Yvi[n][d] = b1[d] + sum_i Vsrc[n][i] * w1[i*128+d]   (16 nodes / block), bf16 out
__global__ __launch_bounds__(256, 4)
void yvi_kernel(const float* __restrict__ Vsrc, const float* __restrict__ w1,
                const float* __restrict__ b1, bf16* __restrict__ out)
{
    __shared__ float sV[16][128];
    const int nb  = blockIdx.x * 16;
    const int tid = threadIdx.x;
    for (int i = tid; i < 16 * 128; i += 256)
        sV[i >> 7][i & 127] = Vsrc[(size_t)nb * 128 + i];
    __syncthreads();
    int d  = tid & 127;
    int n0 = (tid >> 7) * 8;
    float acc[8];
    float bd = b1[d];
    #pragma unroll
    for (int u = 0; u < 8; ++u) acc[u] = bd;
    for (int i = 0; i < 128; ++i) {
        float wv = w1[i * 128 + d];
        #pragma unroll
        for (int u = 0; u < 8; ++u) acc[u] += sV[n0 + u][i] * wv;
    }
    #pragma unroll
    for (int u = 0; u < 8; ++u)
        out[(size_t)(nb + n0 + u) * 128 + d] = __float2bfloat16(acc[u]);
}

// One GEMM stage: A [48][ldA] bf16 in LDS, B packed bf16, 3 M-tiles x 2 N-tiles per wave.
template<int KSBEG, int NSTEPS>
__device__ __forceinline__ void do_gemm(const bf16* A, int ldA, const bf16* Bp,
                                        int lane, int nt0, f32x4 acc[3][2]) {
    #pragma unroll
    for (int s = 0; s < NSTEPS; ++s) {
        int ks = KSBEG + s;
        short8 b0 = *(const short8*)(Bp + (((ks * 8 + nt0) * 64 + lane) << 3));
        short8 b1 = *(const short8*)(Bp + (((ks * 8 + nt0 + 1) * 64 + lane) << 3));
        int kcol = s * 32 + ((lane >> 4) << 3);
        #pragma unroll
        for (int mt = 0; mt < 3; ++mt) {
            short8 a = *(const short8*)(A + (mt * 16 + (lane & 15)) * ldA + kcol);
            acc[mt][0] = __builtin_amdgcn_mfma_f32_16x16x32_bf16(a, b0, acc[mt][0], 0, 0, 0);
            acc[mt][1] = __builtin_amdgcn_mfma_f32_16x16x32_bf16(a, b1, acc[mt][1], 0, 0, 0);
        }
    }
}

// NODE message pass (validated by output-0 pass in rounds 5-8): occupancy-5, aliased LDS.
__global__ __launch_bounds__(256, 5)
void msg_node_kernel(const float* __restrict__ Vf,
                     const float* __restrict__ Ef,
                     const float* __restrict__ maskf,
                     const int*   __restrict__ Kidx,
                     const bf16*  __restrict__ Yvi,
                     const bf16* __restrict__ w1p,
                     const bf16* __restrict__ w2p, const float* __restrict__ b2f,
                     const bf16* __restrict__ w3p, const float* __restrict__ b3f,
                     const float* __restrict__ lng, const float* __restrict__ lnb,
                     const float* __restrict__ Vres,
                     bf16*  __restrict__ V1out)
{
    __shared__ __align__(16) char region0[26112];   // sA[0,25344) ; sH1[0,13056) ; sH2[13056,26112)
    __shared__ float sYvi[128];
    __shared__ float sMask[48];
    __shared__ float sS[128];

    bf16  (*sA)[264]  = reinterpret_cast<bf16(*)[264]>(region0);
    bf16  (*sH1)[136] = reinterpret_cast<bf16(*)[136]>(region0);
    bf16  (*sH2)[136] = reinterpret_cast<bf16(*)[136]>(region0 + 13056);

    const int node = blockIdx.x;
    const int tid  = threadIdx.x;
    const int lane = tid & 63;
    const int wid  = tid >> 6;
    const int z    = node >> 10;
    const int* krow = Kidx + node * KN;

    if (tid < 128) sYvi[tid] = __bfloat162float(Yvi[(size_t)node * 128 + tid]);
    if (tid >= 128 && tid < 128 + KN)
        sMask[tid - 128] = maskf[(size_t)node * KN + (tid - 128)];
    {
        const float* erow0 = Ef + (size_t)node * KN * 128;
        for (int c = tid; c < KN * 32; c += 256) {
            int r = c >> 5;
            int off = (c & 31) * 4;
            int kj = krow[r];
            float4 vj = *(const float4*)(Vf + ((size_t)(z * 1024 + kj)) * 128 + off);
            *(uint2*)&sA[r][off] = pack4(vj.x, vj.y, vj.z, vj.w);
            float4 ee = *(const float4*)(erow0 + r * 128 + off);
            *(uint2*)&sA[r][128 + off] = pack4(ee.x, ee.y, ee.z, ee.w);
        }
    }
    __syncthreads();                                   // B0: sA ready

    const int nt0 = wid * 2;
    const int lm  = lane & 15;
    const int lg  = lane >> 4;
    const f32x4 vzero = {0.f, 0.f, 0.f, 0.f};

    f32x4 acc[3][2];
    #pragma unroll
    for (int mt = 0; mt < 3; ++mt) { acc[mt][0] = vzero; acc[mt][1] = vzero; }
    do_gemm<4, 8>(&sA[0][0], 264, w1p, lane, nt0, acc);
    __syncthreads();                                   // B1: sA reads done (sH1 aliases sA)
    #pragma unroll
    for (int mt = 0; mt < 3; ++mt)
    #pragma unroll
    for (int ni = 0; ni < 2; ++ni) {
        int col = (nt0 + ni) * 16 + lm;
        float yv = sYvi[col];
        #pragma unroll
        for (int r = 0; r < 4; ++r) {
            int row = mt * 16 + lg * 4 + r;
            sH1[row][col] = __float2bfloat16(gelu_f(acc[mt][ni][r] + yv));
        }
    }
    __syncthreads();                                   // B2: sH1 ready

    #pragma unroll
    for (int mt = 0; mt < 3; ++mt) { acc[mt][0] = vzero; acc[mt][1] = vzero; }
    do_gemm<0, 4>(&sH1[0][0], 136, w2p, lane, nt0, acc);
    {
        float bc0 = b2f[nt0 * 16 + lm];
        float bc1 = b2f[(nt0 + 1) * 16 + lm];
        #pragma unroll
        for (int mt = 0; mt < 3; ++mt)
        #pragma unroll
        for (int r = 0; r < 4; ++r) {
            int row = mt * 16 + lg * 4 + r;
            sH2[row][nt0 * 16 + lm]       = __float2bfloat16(gelu_f(acc[mt][0][r] + bc0));
            sH2[row][(nt0 + 1) * 16 + lm] = __float2bfloat16(gelu_f(acc[mt][1][r] + bc1));
        }
    }
    __syncthreads();                                   // B3: sH2 ready

    #pragma unroll
    for (int mt = 0; mt < 3; ++mt) { acc[mt][0] = vzero; acc[mt][1] = vzero; }
    do_gemm<0, 4>(&sH2[0][0], 136, w3p, lane, nt0, acc);
    {
        float bc0 = b3f[nt0 * 16 + lm];
        float bc1 = b3f[(nt0 + 1) * 16 + lm];
        float cs0 = 0.f, cs1 = 0.f;
        #pragma unroll
        for (int mt = 0; mt < 3; ++mt)
        #pragma unroll
        for (int r = 0; r < 4; ++r) {
            float m = sMask[mt * 16 + lg * 4 + r];
            cs0 += (acc[mt][0][r] + bc0) * m;
            cs1 += (acc[mt][1][r] + bc1) * m;
        }
        cs0 += __shfl_xor(cs0, 16); cs0 += __shfl_xor(cs0, 32);
        cs1 += __shfl_xor(cs1, 16); cs1 += __shfl_xor(cs1, 32);
        if (lane < 16) {
            sS[nt0 * 16 + lane]       = cs0;
            sS[(nt0 + 1) * 16 + lane] = cs1;
        }
    }
    __syncthreads();                                   // B5: sS ready

    if (tid < 64) {
        float a = Vres[(size_t)node * 128 + tid]      + sS[tid];
        float b = Vres[(size_t)node * 128 + tid + 64] + sS[tid + 64];
        float s = a + b, q = a * a + b * b;
        #pragma unroll
        for (int off = 32; off; off >>= 1) { s += __shfl_xor(s, off); q += __shfl_xor(q, off); }
        float mean = s * (1.f / 128.f);
        float var  = q * (1.f / 128.f) - mean * mean;
        float rs   = rsqrtf(var + 1e-5f);
        V1out[(size_t)node * 128 + tid] =
            __float2bfloat16((a - mean) * rs * lng[tid] + lnb[tid]);
        V1out[(size_t)node * 128 + tid + 64] =
            __float2bfloat16((b - mean) * rs * lng[tid + 64] + lnb[tid + 64]);
    }
}

// EDGE message pass: ROUND-4-VERBATIM template instantiation (NODE_PASS=false):
// in-kernel y_vi from sVi (f32 V2), launch_bounds(256,2), f32 sMe over sA, R4 barriers.
__global__ __launch_bounds__(256, 2)
void msg_edge_kernel(const float* __restrict__ Vf,     // V2 (f32) gather source
                     const float* __restrict__ ViF,    // V2 (f32) Vi source
                     const float* __restrict__ Ef,
                     const float* __restrict__ maskf,
                     const int*   __restrict__ Kidx,
                     const float* __restrict__ w1raw,  // em_w1 [384][128] f32 (rows 0..127 = Vi part)
                     const bf16* __restrict__ w1p, const float* __restrict__ b1f,
                     const bf16* __restrict__ w2p, const float* __restrict__ b2f,
                     const bf16* __restrict__ w3p, const float* __restrict__ b3f,
                     const float* __restrict__ lng, const float* __restrict__ lnb,
                     float* __restrict__ Eout)
{
    __shared__ __align__(16) char region0[48 * 138 * 4];   // sA (bf16[48][264]) / sMe (f32[48][138])
    __shared__ __align__(16) bf16 sH1[48][136];
    __shared__ __align__(16) bf16 sH2[48][136];
    __shared__ float sVi[128];
    __shared__ float sYvi[128];
    __shared__ float sMask[48];

    bf16  (*sA)[264]  = reinterpret_cast<bf16(*)[264]>(region0);
    float (*sMe)[138] = reinterpret_cast<float(*)[138]>(region0);

    const int node = blockIdx.x;
    const int tid  = threadIdx.x;
    const int lane = tid & 63;
    const int wid  = tid >> 6;
    const int z    = node >> 10;
    const int* krow = Kidx + node * KN;

    // ---- stage Vi (f32), mask, and A rows [Vj | E] (bf16) ----
    if (tid < 128) sVi[tid] = ViF[(size_t)node * 128 + tid];
    if (tid >= 128 && tid < 128 + KN)
        sMask[tid - 128] = maskf[(size_t)node * KN + (tid - 128)];
    {
        const float* erow0 = Ef + (size_t)node * KN * 128;
        for (int c = tid; c < KN * 32; c += 256) {
            int r = c >> 5;
            int off = (c & 31) * 4;
            int kj = krow[r];
            float4 vj = *(const float4*)(Vf + ((size_t)(z * 1024 + kj)) * 128 + off);
            *(uint2*)&sA[r][off] = pack4(vj.x, vj.y, vj.z, vj.w);
            float4 ee = *(const float4*)(erow0 + r * 128 + off);
            *(uint2*)&sA[r][128 + off] = pack4(ee.x, ee.y, ee.z, ee.w);
        }
    }
    __syncthreads();

    // ---- y_vi = b1 + Vi @ w1[0:128,:]  (identical for all 48 rows, f32) ----
    if (tid < 128) {
        float acc = b1f[tid];
        #pragma unroll 4
        for (int i = 0; i < 128; ++i)
            acc += sVi[i] * w1raw[i * 128 + tid];
        sYvi[tid] = acc;
    }
    __syncthreads();

    const int nt0 = wid * 2;
    const int lm  = lane & 15;
    const int lg  = lane >> 4;
    const f32x4 vzero = {0.f, 0.f, 0.f, 0.f};

    // ---- GEMM1: [48][256](Vj|E) @ w1[128:384][:] ----
    f32x4 acc[3][2];
    #pragma unroll
    for (int mt = 0; mt < 3; ++mt) { acc[mt][0] = vzero; acc[mt][1] = vzero; }
    do_gemm<4, 8>(&sA[0][0], 264, w1p, lane, nt0, acc);
    #pragma unroll
    for (int mt = 0; mt < 3; ++mt)
    #pragma unroll
    for (int ni = 0; ni < 2; ++ni) {
        int col = (nt0 + ni) * 16 + lm;
        float yv = sYvi[col];
        #pragma unroll
        for (int r = 0; r < 4; ++r) {
            int row = mt * 16 + lg * 4 + r;
            sH1[row][col] = __float2bfloat16(gelu_f(acc[mt][ni][r] + yv));
        }
    }
    __syncthreads();

    // ---- GEMM2: H1 @ w2 ----
    #pragma unroll
    for (int mt = 0; mt < 3; ++mt) { acc[mt][0] = vzero; acc[mt][1] = vzero; }
    do_gemm<0, 4>(&sH1[0][0], 136, w2p, lane, nt0, acc);
    {
        float bc0 = b2f[nt0 * 16 + lm];
        float bc1 = b2f[(nt0 + 1) * 16 + lm];
        #pragma unroll
        for (int mt = 0; mt < 3; ++mt)
        #pragma unroll
        for (int r = 0; r < 4; ++r) {
            int row = mt * 16 + lg * 4 + r;
            sH2[row][nt0 * 16 + lm]       = __float2bfloat16(gelu_f(acc[mt][0][r] + bc0));
            sH2[row][(nt0 + 1) * 16 + lm] = __float2bfloat16(gelu_f(acc[mt][1][r] + bc1));
        }
    }
    __syncthreads();

    // ---- GEMM3: H2 @ w3, + b3, * mask ----
    #pragma unroll
    for (int mt = 0; mt < 3; ++mt) { acc[mt][0] = vzero; acc[mt][1] = vzero; }
    do_gemm<0, 4>(&sH2[0][0], 136, w3p, lane, nt0, acc);
    __syncthreads();                                   // before sMe overwrites sA region
    {
        float bc0 = b3f[nt0 * 16 + lm];
        float bc1 = b3f[(nt0 + 1) * 16 + lm];
        #pragma unroll
        for (int mt = 0; mt < 3; ++mt)
        #pragma unroll
        for (int r = 0; r < 4; ++r) {
            int row = mt * 16 + lg * 4 + r;
            float m = sMask[row];
            sMe[row][nt0 * 16 + lm]       = (acc[mt][0][r] + bc0) * m;
            sMe[row][(nt0 + 1) * 16 + lm] = (acc[mt][1][r] + bc1) * m;
        }
    }
    __syncthreads();

    // ---- finalize: E = LN(E + Me) ----
    for (int r = wid; r < KN; r += 4) {
        float2 ev = ((const float2*)(Ef + ((size_t)node * KN + r) * 128))[lane];
        float x0 = ev.x + sMe[r][2 * lane];
        float x1 = ev.y + sMe[r][2 * lane + 1];
        float s = x0 + x1, q = x0 * x0 + x1 * x1;
        #pragma unroll
        for (int off = 32; off; off >>= 1) { s += __shfl_xor(s, off); q += __shfl_xor(q, off); }
        float mean = s * (1.f / 128.f);
        float var  = q * (1.f / 128.f) - mean * mean;
        float rs   = rsqrtf(var + 1e-5f);
        float2 o;
        o.x = (x0 - mean) * rs * lng[2 * lane]     + lnb[2 * lane];
        o.y = (x1 - mean) * rs * lng[2 * lane + 1] + lnb[2 * lane + 1];
        ((float2*)(Eout + ((size_t)node * KN + r) * 128))[lane] = o;
    }
}

// FFN: V2 = LN(V1 + gelu(V1@w1+b1)@w2+b2), 16 nodes per block (VALU, f32).
__global__ __launch_bounds__(256, 2)
void ffn_kernel(const bf16* __restrict__ V1,
                const float* __restrict__ w1, const float* __restrict__ b1,   // [128][512], [512]
                const float* __restrict__ w2, const float* __restrict__ b2,   // [512][128], [128]
                const float* __restrict__ g, const float* __restrict__ bta,
                float* __restrict__ Vout)
{
    constexpr int NODES = 16;
    __shared__ float sV[NODES][128];
    __shared__ float sH[NODES][512];
    __shared__ float sX[NODES][128];

    const int nb  = blockIdx.x * NODES;
    const int tid = threadIdx.x;

    for (int i = tid; i < NODES * 128; i += 256)
        sV[i >> 7][i & 127] = __bfloat162float(V1[(size_t)nb * 128 + i]);
    __syncthreads();

    #pragma unroll
    for (int jj = 0; jj < 2; ++jj) {
        int j = tid + jj * 256;
        float acc[NODES];
        float bj = b1[j];
        #pragma unroll
        for (int n = 0; n < NODES; ++n) acc[n] = bj;
        for (int i = 0; i < 128; ++i) {
            float wv = w1[i * 512 + j];
            #pragma unroll
            for (int n = 0; n < NODES; ++n) acc[n] += sV[n][i] * wv;
        }
        #pragma unroll
        for (int n = 0; n < NODES; ++n) sH[n][j] = gelu_f(acc[n]);
    }
    __syncthreads();

    {
        int d  = tid & 127;
        int n0 = (tid >> 7) * 8;
        float acc[8];
        float bd = b2[d];
        #pragma unroll
        for (int u = 0; u < 8; ++u) acc[u] = bd;
        for (int j = 0; j < 512; ++j) {
            float wv = w2[j * 128 + d];
            #pragma unroll
            for (int u = 0; u < 8; ++u) acc[u] += sH[n0 + u][j] * wv;
        }
        #pragma unroll
        for (int u = 0; u < 8; ++u) sX[n0 + u][d] = sV[n0 + u][d] + acc[u];
    }
    __syncthreads();

    const int wid = tid >> 6, lane = tid & 63;
    for (int n = wid; n < NODES; n += 4) {
        float a = sX[n][lane], b = sX[n][lane + 64];
        float s = a + b, q = a * a + b * b;
        #pragma unroll
        for (int off = 32; off; off >>= 1) { s += __shfl_xor(s, off); q += __shfl_xor(q, off); }
        float mean = s * (1.f / 128.f);
        float var  = q * (1.f / 128.f) - mean * mean;
        float rs   = rsqrtf(var + 1e-5f);
        size_t base = (size_t)(nb + n) * 128;
        Vout[base + lane]      = (a - mean) * rs * g[lane]      + bta[lane];
        Vout[base + lane + 64] = (b - mean) * rs * g[lane + 64] + bta[lane + 64];
    }
}

extern "C" void kernel_launch(void* const* d_in, const int* in_sizes, int n_in,
                              void* d_out, int out_size, void* d_ws, size_t ws_size,
                              hipStream_t stream) {
    const float* V     = (const float*)d_in[0];
    const float* E     = (const float*)d_in[1];
    const float* emask = (const float*)d_in[2];
    const float* nm_w1 = (const float*)d_in[3];
    const float* nm_b1 = (const float*)d_in[4];
    const float* nm_w2 = (const float*)d_in[5];
    const float* nm_b2 = (const float*)d_in[6];
    const float* nm_w3 = (const float*)d_in[7];
    const float* nm_b3 = (const float*)d_in[8];
    const float* nmn_g = (const float*)d_in[9];
    const float* nmn_b = (const float*)d_in[10];
    const float* ffn_w1 = (const float*)d_in[11];
    const float* ffn_b1 = (const float*)d_in[12];
    const float* ffn_w2 = (const float*)d_in[13];
    const float* ffn_b2 = (const float*)d_in[14];
    const float* fn_g  = (const float*)d_in[15];
    const float* fn_b  = (const float*)d_in[16];
    const float* em_w1 = (const float*)d_in[17];
    const float* em_b1 = (const float*)d_in[18];
    const float* em_w2 = (const float*)d_in[19];
    const float* em_b2 = (const float*)d_in[20];
    const float* em_w3 = (const float*)d_in[21];
    const float* em_b3 = (const float*)d_in[22];
    const float* emn_g = (const float*)d_in[23];
    const float* emn_b = (const float*)d_in[24];
    const int*  K     = (const int*)d_in[25];

    // ws layout:
    //   [0, 327680)            packed weights (bf16, 6 segments, round-4 offsets)
    //   [327680, +1MB)         V1f (bf16)
    //   [327680+1MB, +2MB)     YviN (bf16)
    char* ws = (char*)d_ws;
    bf16* p_nm_w1 = (bf16*)(ws);
    bf16* p_nm_w2 = (bf16*)(ws + 98304);
    bf16* p_nm_w3 = (bf16*)(ws + 131072);
    bf16* p_em_w1 = (bf16*)(ws + 163840);
    bf16* p_em_w2 = (bf16*)(ws + 262144);
    bf16* p_em_w3 = (bf16*)(ws + 294912);
    bf16* V1f  = (bf16*)(ws + 327680);
    bf16* YviN = (bf16*)(ws + 327680 + 1048576);

    float* V2out = (float*)d_out;                 // [4,1024,128] f32
    float* Eout  = (float*)d_out + 524288;        // [4,1024,48,128] f32

    // round-4-verbatim packing (six launches)
    pack_b_kernel<<<192, 256, 0, stream>>>(nm_w1, p_nm_w1, 49152);
    pack_b_kernel<<<64,  256, 0, stream>>>(nm_w2, p_nm_w2, 16384);
    pack_b_kernel<<<64,  256, 0, stream>>>(nm_w3, p_nm_w3, 16384);
    pack_b_kernel<<<192, 256, 0, stream>>>(em_w1, p_em_w1, 49152);
    pack_b_kernel<<<64,  256, 0, stream>>>(em_w2, p_em_w2, 16384);
    pack_b_kernel<<<64,  256, 0, stream>>>(em_w3, p_em_w3, 16384);

    yvi_kernel<<<ZN / 16, 256, 0, stream>>>(V, nm_w1, nm_b1, YviN);

    msg_node_kernel<<<ZN, 256, 0, stream>>>(
        V, E, emask, K, YviN,
        p_nm_w1, p_nm_w2, nm_b2, p_nm_w3, nm_b3,
        nmn_g, nmn_b, V, V1f);

    ffn_kernel<<<ZN / 16, 256, 0, stream>>>(
        V1f, ffn_w1, ffn_b1, ffn_w2, ffn_b2, fn_g, fn_b, V2out);

    // round-4-verbatim edge pass: in-kernel y_vi from f32 V2 (no YviE chain)
    msg_edge_kernel<<<ZN, 256, 0, stream>>>(
        V2out, V2out, E, emask, K,
        em_w1, p_em_w1, em_b1, p_em_w2, em_b2, p_em_w3, em_b3,
        emn_g, emn_b, Eout);
}

// Round 11
// 260.220 us; speedup vs baseline: 1.5440x; 1.3357x over previous
//
#include <hip/hip_runtime.h>
#include <hip/hip_bf16.h>

using bf16 = __hip_bfloat16;
typedef __attribute__((ext_vector_type(8))) short short8;
typedef __attribute__((ext_vector_type(4))) float f32x4;

#define ZN 4096
#define KN 48

__device__ __forceinline__ float gelu_f(float x) {
    return 0.5f * x * (1.0f + erff(x * 0.70710678118654752440f));
}

__device__ __forceinline__ uint2 pack4(float a, float b, float c, float d) {
    union { bf16 h[4]; uint2 u; } t;
    t.h[0] = __float2bfloat16(a); t.h[1] = __float2bfloat16(b);
    t.h[2] = __float2bfloat16(c); t.h[3] = __float2bfloat16(d);
    return t.u;
}

// Pack all six W[K][128] (row-major f32) into one contiguous bf16 MFMA B-fragment buffer.
// (Exonerated vs 6x pack_b by R5==R6 bit-identical outputs.)
__global__ void pack_all_kernel(const float* __restrict__ nm1, const float* __restrict__ nm2,
                                const float* __restrict__ nm3, const float* __restrict__ em1,
                                const float* __restrict__ em2, const float* __restrict__ em3,
                                bf16* __restrict__ P) {
    int idx = blockIdx.x * 256 + threadIdx.x;          // 0 .. 163839
    const float* W; int local;
    if      (idx <  49152) { W = nm1; local = idx;          }
    else if (idx <  65536) { W = nm2; local = idx -  49152; }
    else if (idx <  81920) { W = nm3; local = idx -  65536; }
    else if (idx < 131072) { W = em1; local = idx -  81920; }
    else if (idx < 147456) { W = em2; local = idx - 131072; }
    else                   { W = em3; local = idx - 147456; }
    int j    = local & 7;
    int lane = (local >> 3) & 63;
    int nt   = (local >> 9) & 7;
    int ks   = local >> 12;
    int k = ks * 32 + ((lane >> 4) << 3) + j;
    int n = nt * 16 + (lane & 15);
    P[idx] = __float2bfloat16(W[k * 128 + n]);
}

// Yvi[n][d] = b1[d] + sum_i Vsrc[n][i] * w1[i*128+d]   (16 nodes / block), bf16 out.
// Mechanism validated 6x via YviN; values-safe for edge (bounded Yvi attenuated 25x).
__global__ __launch_bounds__(256, 4)
void yvi_kernel(const float* __restrict__ Vsrc, const float* __restrict__ w1,
                const float* __restrict__ b1, bf16* __restrict__ out)
{
    __shared__ float sV[16][128];
    const int nb  = blockIdx.x * 16;
    const int tid = threadIdx.x;
    for (int i = tid; i < 16 * 128; i += 256)
        sV[i >> 7][i & 127] = Vsrc[(size_t)nb * 128 + i];
    __syncthreads();
    int d  = tid & 127;
    int n0 = (tid >> 7) * 8;
    float acc[8];
    float bd = b1[d];
    #pragma unroll
    for (int u = 0; u < 8; ++u) acc[u] = bd;
    for (int i = 0; i < 128; ++i) {
        float wv = w1[i * 128 + d];
        #pragma unroll
        for (int u = 0; u < 8; ++u) acc[u] += sV[n0 + u][i] * wv;
    }
    #pragma unroll
    for (int u = 0; u < 8; ++u)
        out[(size_t)(nb + n0 + u) * 128 + d] = __float2bfloat16(acc[u]);
}

// One GEMM stage: A [48][ldA] bf16 in LDS, B packed bf16, 3 M-tiles x 2 N-tiles per wave.
template<int KSBEG, int NSTEPS>
__device__ __forceinline__ void do_gemm(const bf16* A, int ldA, const bf16* Bp,
                                        int lane, int nt0, f32x4 acc[3][2]) {
    #pragma unroll
    for (int s = 0; s < NSTEPS; ++s) {
        int ks = KSBEG + s;
        short8 b0 = *(const short8*)(Bp + (((ks * 8 + nt0) * 64 + lane) << 3));
        short8 b1 = *(const short8*)(Bp + (((ks * 8 + nt0 + 1) * 64 + lane) << 3));
        int kcol = s * 32 + ((lane >> 4) << 3);
        #pragma unroll
        for (int mt = 0; mt < 3; ++mt) {
            short8 a = *(const short8*)(A + (mt * 16 + (lane & 15)) * ldA + kcol);
            acc[mt][0] = __builtin_amdgcn_mfma_f32_16x16x32_bf16(a, b0, acc[mt][0], 0, 0, 0);
            acc[mt][1] = __builtin_amdgcn_mfma_f32_16x16x32_bf16(a, b1, acc[mt][1], 0, 0, 0);
        }
    }
}

// NODE message pass (validated rounds 5-10): occupancy-5, aliased LDS, Yvi buffer.
__global__ __launch_bounds__(256, 5)
void msg_node_kernel(const float* __restrict__ Vf,
                     const float* __restrict__ Ef,
                     const float* __restrict__ maskf,
                     const int*   __restrict__ Kidx,
                     const bf16*  __restrict__ Yvi,
                     const bf16* __restrict__ w1p,
                     const bf16* __restrict__ w2p, const float* __restrict__ b2f,
                     const bf16* __restrict__ w3p, const float* __restrict__ b3f,
                     const float* __restrict__ lng, const float* __restrict__ lnb,
                     const float* __restrict__ Vres,
                     bf16*  __restrict__ V1out)
{
    __shared__ __align__(16) char region0[26112];   // sA[0,25344) ; sH1[0,13056) ; sH2[13056,26112)
    __shared__ float sYvi[128];
    __shared__ float sMask[48];
    __shared__ float sS[128];

    bf16  (*sA)[264]  = reinterpret_cast<bf16(*)[264]>(region0);
    bf16  (*sH1)[136] = reinterpret_cast<bf16(*)[136]>(region0);
    bf16  (*sH2)[136] = reinterpret_cast<bf16(*)[136]>(region0 + 13056);

    const int node = blockIdx.x;
    const int tid  = threadIdx.x;
    const int lane = tid & 63;
    const int wid  = tid >> 6;
    const int z    = node >> 10;
    const int* krow = Kidx + node * KN;

    if (tid < 128) sYvi[tid] = __bfloat162float(Yvi[(size_t)node * 128 + tid]);
    if (tid >= 128 && tid < 128 + KN)
        sMask[tid - 128] = maskf[(size_t)node * KN + (tid - 128)];
    {
        const float* erow0 = Ef + (size_t)node * KN * 128;
        for (int c = tid; c < KN * 32; c += 256) {
            int r = c >> 5;
            int off = (c & 31) * 4;
            int kj = krow[r];
            float4 vj = *(const float4*)(Vf + ((size_t)(z * 1024 + kj)) * 128 + off);
            *(uint2*)&sA[r][off] = pack4(vj.x, vj.y, vj.z, vj.w);
            float4 ee = *(const float4*)(erow0 + r * 128 + off);
            *(uint2*)&sA[r][128 + off] = pack4(ee.x, ee.y, ee.z, ee.w);
        }
    }
    __syncthreads();                                   // B0: sA ready

    const int nt0 = wid * 2;
    const int lm  = lane & 15;
    const int lg  = lane >> 4;
    const f32x4 vzero = {0.f, 0.f, 0.f, 0.f};

    f32x4 acc[3][2];
    #pragma unroll
    for (int mt = 0; mt < 3; ++mt) { acc[mt][0] = vzero; acc[mt][1] = vzero; }
    do_gemm<4, 8>(&sA[0][0], 264, w1p, lane, nt0, acc);
    __syncthreads();                                   // B1: sA reads done (sH1 aliases sA)
    #pragma unroll
    for (int mt = 0; mt < 3; ++mt)
    #pragma unroll
    for (int ni = 0; ni < 2; ++ni) {
        int col = (nt0 + ni) * 16 + lm;
        float yv = sYvi[col];
        #pragma unroll
        for (int r = 0; r < 4; ++r) {
            int row = mt * 16 + lg * 4 + r;
            sH1[row][col] = __float2bfloat16(gelu_f(acc[mt][ni][r] + yv));
        }
    }
    __syncthreads();                                   // B2: sH1 ready

    #pragma unroll
    for (int mt = 0; mt < 3; ++mt) { acc[mt][0] = vzero; acc[mt][1] = vzero; }
    do_gemm<0, 4>(&sH1[0][0], 136, w2p, lane, nt0, acc);
    {
        float bc0 = b2f[nt0 * 16 + lm];
        float bc1 = b2f[(nt0 + 1) * 16 + lm];
        #pragma unroll
        for (int mt = 0; mt < 3; ++mt)
        #pragma unroll
        for (int r = 0; r < 4; ++r) {
            int row = mt * 16 + lg * 4 + r;
            sH2[row][nt0 * 16 + lm]       = __float2bfloat16(gelu_f(acc[mt][0][r] + bc0));
            sH2[row][(nt0 + 1) * 16 + lm] = __float2bfloat16(gelu_f(acc[mt][1][r] + bc1));
        }
    }
    __syncthreads();                                   // B3: sH2 ready

    #pragma unroll
    for (int mt = 0; mt < 3; ++mt) { acc[mt][0] = vzero; acc[mt][1] = vzero; }
    do_gemm<0, 4>(&sH2[0][0], 136, w3p, lane, nt0, acc);
    {
        float bc0 = b3f[nt0 * 16 + lm];
        float bc1 = b3f[(nt0 + 1) * 16 + lm];
        float cs0 = 0.f, cs1 = 0.f;
        #pragma unroll
        for (int mt = 0; mt < 3; ++mt)
        #pragma unroll
        for (int r = 0; r < 4; ++r) {
            float m = sMask[mt * 16 + lg * 4 + r];
            cs0 += (acc[mt][0][r] + bc0) * m;
            cs1 += (acc[mt][1][r] + bc1) * m;
        }
        cs0 += __shfl_xor(cs0, 16); cs0 += __shfl_xor(cs0, 32);
        cs1 += __shfl_xor(cs1, 16); cs1 += __shfl_xor(cs1, 32);
        if (lane < 16) {
            sS[nt0 * 16 + lane]       = cs0;
            sS[(nt0 + 1) * 16 + lane] = cs1;
        }
    }
    __syncthreads();                                   // B5: sS ready

    if (tid < 64) {
        float a = Vres[(size_t)node * 128 + tid]      + sS[tid];
        float b = Vres[(size_t)node * 128 + tid + 64] + sS[tid + 64];
        float s = a + b, q = a * a + b * b;
        #pragma unroll
        for (int off = 32; off; off >>= 1) { s += __shfl_xor(s, off); q += __shfl_xor(q, off); }
        float mean = s * (1.f / 128.f);
        float var  = q * (1.f / 128.f) - mean * mean;
        float rs   = rsqrtf(var + 1e-5f);
        V1out[(size_t)node * 128 + tid] =
            __float2bfloat16((a - mean) * rs * lng[tid] + lnb[tid]);
        V1out[(size_t)node * 128 + tid + 64] =
            __float2bfloat16((b - mean) * rs * lng[tid + 64] + lnb[tid + 64]);
    }
}

// EDGE MLP kernel: clone of msg_node_kernel with GEMM3 epilogue writing Me*mask
// DIRECTLY to global f32 (no sMe in LDS, no finalize). Me lands in Eout's slot.
__global__ __launch_bounds__(256, 5)
void mlp_edge_kernel(const float* __restrict__ Vf,     // V2 (f32) gather source
                     const float* __restrict__ Ef,
                     const float* __restrict__ maskf,
                     const int*   __restrict__ Kidx,
                     const bf16*  __restrict__ Yvi,    // YviE (bf16)
                     const bf16* __restrict__ w1p,
                     const bf16* __restrict__ w2p, const float* __restrict__ b2f,
                     const bf16* __restrict__ w3p, const float* __restrict__ b3f,
                     float* __restrict__ MeOut)        // f32 [4096*48][128] (= Eout slot)
{
    __shared__ __align__(16) char region0[26112];
    __shared__ float sYvi[128];
    __shared__ float sMask[48];

    bf16  (*sA)[264]  = reinterpret_cast<bf16(*)[264]>(region0);
    bf16  (*sH1)[136] = reinterpret_cast<bf16(*)[136]>(region0);
    bf16  (*sH2)[136] = reinterpret_cast<bf16(*)[136]>(region0 + 13056);

    const int node = blockIdx.x;
    const int tid  = threadIdx.x;
    const int lane = tid & 63;
    const int wid  = tid >> 6;
    const int z    = node >> 10;
    const int* krow = Kidx + node * KN;

    if (tid < 128) sYvi[tid] = __bfloat162float(Yvi[(size_t)node * 128 + tid]);
    if (tid >= 128 && tid < 128 + KN)
        sMask[tid - 128] = maskf[(size_t)node * KN + (tid - 128)];
    {
        const float* erow0 = Ef + (size_t)node * KN * 128;
        for (int c = tid; c < KN * 32; c += 256) {
            int r = c >> 5;
            int off = (c & 31) * 4;
            int kj = krow[r];
            float4 vj = *(const float4*)(Vf + ((size_t)(z * 1024 + kj)) * 128 + off);
            *(uint2*)&sA[r][off] = pack4(vj.x, vj.y, vj.z, vj.w);
            float4 ee = *(const float4*)(erow0 + r * 128 + off);
            *(uint2*)&sA[r][128 + off] = pack4(ee.x, ee.y, ee.z, ee.w);
        }
    }
    __syncthreads();                                   // B0

    const int nt0 = wid * 2;
    const int lm  = lane & 15;
    const int lg  = lane >> 4;
    const f32x4 vzero = {0.f, 0.f, 0.f, 0.f};

    f32x4 acc[3][2];
    #pragma unroll
    for (int mt = 0; mt < 3; ++mt) { acc[mt][0] = vzero; acc[mt][1] = vzero; }
    do_gemm<4, 8>(&sA[0][0], 264, w1p, lane, nt0, acc);
    __syncthreads();                                   // B1
    #pragma unroll
    for (int mt = 0; mt < 3; ++mt)
    #pragma unroll
    for (int ni = 0; ni < 2; ++ni) {
        int col = (nt0 + ni) * 16 + lm;
        float yv = sYvi[col];
        #pragma unroll
        for (int r = 0; r < 4; ++r) {
            int row = mt * 16 + lg * 4 + r;
            sH1[row][col] = __float2bfloat16(gelu_f(acc[mt][ni][r] + yv));
        }
    }
    __syncthreads();                                   // B2

    #pragma unroll
    for (int mt = 0; mt < 3; ++mt) { acc[mt][0] = vzero; acc[mt][1] = vzero; }
    do_gemm<0, 4>(&sH1[0][0], 136, w2p, lane, nt0, acc);
    {
        float bc0 = b2f[nt0 * 16 + lm];
        float bc1 = b2f[(nt0 + 1) * 16 + lm];
        #pragma unroll
        for (int mt = 0; mt < 3; ++mt)
        #pragma unroll
        for (int r = 0; r < 4; ++r) {
            int row = mt * 16 + lg * 4 + r;
            sH2[row][nt0 * 16 + lm]       = __float2bfloat16(gelu_f(acc[mt][0][r] + bc0));
            sH2[row][(nt0 + 1) * 16 + lm] = __float2bfloat16(gelu_f(acc[mt][1][r] + bc1));
        }
    }
    __syncthreads();                                   // B3

    #pragma unroll
    for (int mt = 0; mt < 3; ++mt) { acc[mt][0] = vzero; acc[mt][1] = vzero; }
    do_gemm<0, 4>(&sH2[0][0], 136, w3p, lane, nt0, acc);
    {
        float bc0 = b3f[nt0 * 16 + lm];
        float bc1 = b3f[(nt0 + 1) * 16 + lm];
        float* meRow = MeOut + (size_t)node * KN * 128;
        #pragma unroll
        for (int mt = 0; mt < 3; ++mt)
        #pragma unroll
        for (int r = 0; r < 4; ++r) {
            int row = mt * 16 + lg * 4 + r;
            float m = sMask[row];
            meRow[row * 128 + nt0 * 16 + lm]       = (acc[mt][0][r] + bc0) * m;
            meRow[row * 128 + (nt0 + 1) * 16 + lm] = (acc[mt][1][r] + bc1) * m;
        }
    }
    // no finalize, no trailing barrier
}

// EDGE LN kernel: in-place E = LN(E + Me). One wave per row; each thread reads and
// writes only its own 2 elements (no cross-thread in-place hazard).
__global__ __launch_bounds__(256, 8)
void ln_edge_kernel(const float* __restrict__ Ef,
                    float* __restrict__ Me,            // in Eout, read Me / write result
                    const float* __restrict__ g, const float* __restrict__ b)
{
    const int row  = blockIdx.x * 4 + (threadIdx.x >> 6);
    const int lane = threadIdx.x & 63;
    const size_t base = (size_t)row * 128;
    float2 me = ((const float2*)(Me + base))[lane];
    float2 ev = ((const float2*)(Ef + base))[lane];
    float x0 = ev.x + me.x;
    float x1 = ev.y + me.y;
    float s = x0 + x1, q = x0 * x0 + x1 * x1;
    #pragma unroll
    for (int off = 32; off; off >>= 1) { s += __shfl_xor(s, off); q += __shfl_xor(q, off); }
    float mean = s * (1.f / 128.f);
    float var  = q * (1.f / 128.f) - mean * mean;
    float rs   = rsqrtf(var + 1e-5f);
    float2 o;
    o.x = (x0 - mean) * rs * g[2 * lane]     + b[2 * lane];
    o.y = (x1 - mean) * rs * g[2 * lane + 1] + b[2 * lane + 1];
    ((float2*)(Me + base))[lane] = o;
}

// FFN: V2 = LN(V1 + gelu(V1@w1+b1)@w2+b2), 16 nodes per block (VALU, f32).
__global__ __launch_bounds__(256, 2)
void ffn_kernel(const bf16* __restrict__ V1,
                const float* __restrict__ w1, const float* __restrict__ b1,   // [128][512], [512]
                const float* __restrict__ w2, const float* __restrict__ b2,   // [512][128], [128]
                const float* __restrict__ g, const float* __restrict__ bta,
                float* __restrict__ Vout)
{
    constexpr int NODES = 16;
    __shared__ float sV[NODES][128];
    __shared__ float sH[NODES][512];
    __shared__ float sX[NODES][128];

    const int nb  = blockIdx.x * NODES;
    const int tid = threadIdx.x;

    for (int i = tid; i < NODES * 128; i += 256)
        sV[i >> 7][i & 127] = __bfloat162float(V1[(size_t)nb * 128 + i]);
    __syncthreads();

    #pragma unroll
    for (int jj = 0; jj < 2; ++jj) {
        int j = tid + jj * 256;
        float acc[NODES];
        float bj = b1[j];
        #pragma unroll
        for (int n = 0; n < NODES; ++n) acc[n] = bj;
        for (int i = 0; i < 128; ++i) {
            float wv = w1[i * 512 + j];
            #pragma unroll
            for (int n = 0; n < NODES; ++n) acc[n] += sV[n][i] * wv;
        }
        #pragma unroll
        for (int n = 0; n < NODES; ++n) sH[n][j] = gelu_f(acc[n]);
    }
    __syncthreads();

    {
        int d  = tid & 127;
        int n0 = (tid >> 7) * 8;
        float acc[8];
        float bd = b2[d];
        #pragma unroll
        for (int u = 0; u < 8; ++u) acc[u] = bd;
        for (int j = 0; j < 512; ++j) {
            float wv = w2[j * 128 + d];
            #pragma unroll
            for (int u = 0; u < 8; ++u) acc[u] += sH[n0 + u][j] * wv;
        }
        #pragma unroll
        for (int u = 0; u < 8; ++u) sX[n0 + u][d] = sV[n0 + u][d] + acc[u];
    }
    __syncthreads();

    const int wid = tid >> 6, lane = tid & 63;
    for (int n = wid; n < NODES; n += 4) {
        float a = sX[n][lane], b = sX[n][lane + 64];
        float s = a + b, q = a * a + b * b;
        #pragma unroll
        for (int off = 32; off; off >>= 1) { s += __shfl_xor(s, off); q += __shfl_xor(q, off); }
        float mean = s * (1.f / 128.f);
        float var  = q * (1.f / 128.f) - mean * mean;
        float rs   = rsqrtf(var + 1e-5f);
        size_t base = (size_t)(nb + n) * 128;
        Vout[base + lane]      = (a - mean) * rs * g[lane]      + bta[lane];
        Vout[base + lane + 64] = (b - mean) * rs * g[lane + 64] + bta[lane + 64];
    }
}

extern "C" void kernel_launch(void* const* d_in, const int* in_sizes, int n_in,
                              void* d_out, int out_size, void* d_ws, size_t ws_size,
                              hipStream_t stream) {
    const float* V     = (const float*)d_in[0];
    const float* E     = (const float*)d_in[1];
    const float* emask = (const float*)d_in[2];
    const float* nm_w1 = (const float*)d_in[3];
    const float* nm_b1 = (const float*)d_in[4];
    const float* nm_w2 = (const float*)d_in[5];
    const float* nm_b2 = (const float*)d_in[6];
    const float* nm_w3 = (const float*)d_in[7];
    const float* nm_b3 = (const float*)d_in[8];
    const float* nmn_g = (const float*)d_in[9];
    const float* nmn_b = (const float*)d_in[10];
    const float* ffn_w1 = (const float*)d_in[11];
    const float* ffn_b1 = (const float*)d_in[12];
    const float* ffn_w2 = (const float*)d_in[13];
    const float* ffn_b2 = (const float*)d_in[14];
    const float* fn_g  = (const float*)d_in[15];
    const float* fn_b  = (const float*)d_in[16];
    const float* em_w1 = (const float*)d_in[17];
    const float* em_b1 = (const float*)d_in[18];
    const float* em_w2 = (const float*)d_in[19];
    const float* em_b2 = (const float*)d_in[20];
    const float* em_w3 = (const float*)d_in[21];
    const float* em_b3 = (const float*)d_in[22];
    const float* emn_g = (const float*)d_in[23];
    const float* emn_b = (const float*)d_in[24];
    const int*  K     = (const int*)d_in[25];

    // ws layout:
    //   [0, 327680)            packed weights (bf16, 6 segments)
    //   [327680, +1MB)         V1f (bf16) -- reused as YviE after ffn
    //   [327680+1MB, +2MB)     YviN (bf16)
    char* ws = (char*)d_ws;
    bf16* Pall    = (bf16*)(ws);
    bf16* p_nm_w1 = (bf16*)(ws);
    bf16* p_nm_w2 = (bf16*)(ws + 98304);
    bf16* p_nm_w3 = (bf16*)(ws + 131072);
    bf16* p_em_w1 = (bf16*)(ws + 163840);
    bf16* p_em_w2 = (bf16*)(ws + 262144);
    bf16* p_em_w3 = (bf16*)(ws + 294912);
    bf16* V1f  = (bf16*)(ws + 327680);
    bf16* YviE = (bf16*)(ws + 327680);             // reuses V1f slot (dead after ffn)
    bf16* YviN = (bf16*)(ws + 327680 + 1048576);

    float* V2out = (float*)d_out;                 // [4,1024,128] f32
    float* Eout  = (float*)d_out + 524288;        // [4,1024,48,128] f32 (Me staged here first)

    pack_all_kernel<<<640, 256, 0, stream>>>(nm_w1, nm_w2, nm_w3, em_w1, em_w2, em_w3, Pall);

    yvi_kernel<<<ZN / 16, 256, 0, stream>>>(V, nm_w1, nm_b1, YviN);

    msg_node_kernel<<<ZN, 256, 0, stream>>>(
        V, E, emask, K, YviN,
        p_nm_w1, p_nm_w2, nm_b2, p_nm_w3, nm_b3,
        nmn_g, nmn_b, V, V1f);

    ffn_kernel<<<ZN / 16, 256, 0, stream>>>(
        V1f, ffn_w1, ffn_b1, ffn_w2, ffn_b2, fn_g, fn_b, V2out);

    yvi_kernel<<<ZN / 16, 256, 0, stream>>>(V2out, em_w1, em_b1, YviE);

    mlp_edge_kernel<<<ZN, 256, 0, stream>>>(
        V2out, E, emask, K, YviE,
        p_em_w1, p_em_w2, em_b2, p_em_w3, em_b3,
        Eout);

    ln_edge_kernel<<<ZN * KN / 4, 256, 0, stream>>>(E, Eout, emn_g, emn_b);
}

// Round 12
// 192.404 us; speedup vs baseline: 2.0883x; 1.3525x over previous
//
#include <hip/hip_runtime.h>
#include <hip/hip_bf16.h>

using bf16 = __hip_bfloat16;
typedef __attribute__((ext_vector_type(8))) short short8;
typedef __attribute__((ext_vector_type(4))) float f32x4;

#define ZN 4096
#define KN 48

__device__ __forceinline__ float gelu_f(float x) {
    return 0.5f * x * (1.0f + erff(x * 0.70710678118654752440f));
}

__device__ __forceinline__ uint2 pack4(float a, float b, float c, float d) {
    union { bf16 h[4]; uint2 u; } t;
    t.h[0] = __float2bfloat16(a); t.h[1] = __float2bfloat16(b);
    t.h[2] = __float2bfloat16(c); t.h[3] = __float2bfloat16(d);
    return t.u;
}

// Pack all six msg W[K][128] (row-major f32) into one contiguous bf16 MFMA B-fragment buffer.
__global__ void pack_all_kernel(const float* __restrict__ nm1, const float* __restrict__ nm2,
                                const float* __restrict__ nm3, const float* __restrict__ em1,
                                const float* __restrict__ em2, const float* __restrict__ em3,
                                bf16* __restrict__ P) {
    int idx = blockIdx.x * 256 + threadIdx.x;          // 0 .. 163839
    const float* W; int local;
    if      (idx <  49152) { W = nm1; local = idx;          }
    else if (idx <  65536) { W = nm2; local = idx -  49152; }
    else if (idx <  81920) { W = nm3; local = idx -  65536; }
    else if (idx < 131072) { W = em1; local = idx -  81920; }
    else if (idx < 147456) { W = em2; local = idx - 131072; }
    else                   { W = em3; local = idx - 147456; }
    int j    = local & 7;
    int lane = (local >> 3) & 63;
    int nt   = (local >> 9) & 7;
    int ks   = local >> 12;
    int k = ks * 32 + ((lane >> 4) << 3) + j;
    int n = nt * 16 + (lane & 15);
    P[idx] = __float2bfloat16(W[k * 128 + n]);
}

// Pack ffn weights: w1 [128][512] (NT=32, ks 0..3), w2 [512][128] (NT=8, ks 0..15).
__global__ void pack_ffn_kernel(const float* __restrict__ w1, const float* __restrict__ w2,
                                bf16* __restrict__ P1, bf16* __restrict__ P2) {
    int idx = blockIdx.x * 256 + threadIdx.x;          // 0 .. 131071
    if (idx < 65536) {
        int local = idx;
        int j = local & 7, lane = (local >> 3) & 63, nt = (local >> 9) & 31, ks = local >> 14;
        int k = ks * 32 + ((lane >> 4) << 3) + j;
        int n = nt * 16 + (lane & 15);
        P1[local] = __float2bfloat16(w1[k * 512 + n]);
    } else {
        int local = idx - 65536;
        int j = local & 7, lane = (local >> 3) & 63, nt = (local >> 9) & 7, ks = local >> 12;
        int k = ks * 32 + ((lane >> 4) << 3) + j;
        int n = nt * 16 + (lane & 15);
        P2[local] = __float2bfloat16(w2[k * 128 + n]);
    }
}

// 3-Mtile GEMM stage (msg kernels): A [48][ldA] bf16 in LDS, B packed (NT=8).
template<int KSBEG, int NSTEPS>
__device__ __forceinline__ void do_gemm(const bf16* A, int ldA, const bf16* Bp,
                                        int lane, int nt0, f32x4 acc[3][2]) {
    #pragma unroll
    for (int s = 0; s < NSTEPS; ++s) {
        int ks = KSBEG + s;
        short8 b0 = *(const short8*)(Bp + (((ks * 8 + nt0) * 64 + lane) << 3));
        short8 b1 = *(const short8*)(Bp + (((ks * 8 + nt0 + 1) * 64 + lane) << 3));
        int kcol = s * 32 + ((lane >> 4) << 3);
        #pragma unroll
        for (int mt = 0; mt < 3; ++mt) {
            short8 a = *(const short8*)(A + (mt * 16 + (lane & 15)) * ldA + kcol);
            acc[mt][0] = __builtin_amdgcn_mfma_f32_16x16x32_bf16(a, b0, acc[mt][0], 0, 0, 0);
            acc[mt][1] = __builtin_amdgcn_mfma_f32_16x16x32_bf16(a, b1, acc[mt][1], 0, 0, 0);
        }
    }
}

// 1-Mtile GEMM stage: A [16][ldA] bf16 in LDS, B packed with NT n-tiles per ks.
template<int NSTEPS, int NT, int NACC>
__device__ __forceinline__ void do_gemm_1m(const bf16* A, int ldA, const bf16* Bp,
                                           int lane, int nt0, f32x4 acc[NACC]) {
    #pragma unroll
    for (int s = 0; s < NSTEPS; ++s) {
        int kcol = s * 32 + ((lane >> 4) << 3);
        short8 a = *(const short8*)(A + (lane & 15) * ldA + kcol);
        #pragma unroll
        for (int ni = 0; ni < NACC; ++ni) {
            short8 b = *(const short8*)(Bp + (((s * NT + nt0 + ni) * 64 + lane) << 3));
            acc[ni] = __builtin_amdgcn_mfma_f32_16x16x32_bf16(a, b, acc[ni], 0, 0, 0);
        }
    }
}

// Yvi[n][:] = b1 + Vsrc[n]@w1[0:128,:] via MFMA, using ks 0..3 of the packed msg w1.
__global__ __launch_bounds__(256, 4)
void yvi_mfma_kernel(const float* __restrict__ Vsrc, const bf16* __restrict__ w1p,
                     const float* __restrict__ b1f, bf16* __restrict__ out)
{
    __shared__ __align__(16) bf16 sA[16][136];
    const int nb  = blockIdx.x * 16;
    const int tid = threadIdx.x;
    const int lane = tid & 63, wid = tid >> 6;
    for (int c = tid; c < 16 * 32; c += 256) {
        int r = c >> 5, off = (c & 31) * 4;
        float4 v = *(const float4*)(Vsrc + (size_t)(nb + r) * 128 + off);
        *(uint2*)&sA[r][off] = pack4(v.x, v.y, v.z, v.w);
    }
    __syncthreads();
    const int nt0 = wid * 2;
    f32x4 acc[2];
    acc[0] = (f32x4){0.f,0.f,0.f,0.f}; acc[1] = (f32x4){0.f,0.f,0.f,0.f};
    do_gemm_1m<4, 8, 2>(&sA[0][0], 136, w1p, lane, nt0, acc);
    const int lm = lane & 15, lg = lane >> 4;
    #pragma unroll
    for (int ni = 0; ni < 2; ++ni) {
        int col = (nt0 + ni) * 16 + lm;
        float bv = b1f[col];
        #pragma unroll
        for (int r = 0; r < 4; ++r)
            out[(size_t)(nb + lg * 4 + r) * 128 + col] = __float2bfloat16(acc[ni][r] + bv);
    }
}

// FFN via MFMA: V2 = LN(V1 + gelu(V1@w1+b1)@w2+b2), 16 nodes/block.
__global__ __launch_bounds__(256, 2)
void ffn_mfma_kernel(const bf16* __restrict__ V1,
                     const bf16* __restrict__ w1p, const float* __restrict__ b1,
                     const bf16* __restrict__ w2p, const float* __restrict__ b2,
                     const float* __restrict__ g, const float* __restrict__ bta,
                     float* __restrict__ Vout)
{
    __shared__ __align__(16) bf16 sA[16][136];
    __shared__ __align__(16) bf16 sH[16][520];
    __shared__ float sX[16][132];
    const int nb  = blockIdx.x * 16;
    const int tid = threadIdx.x;
    const int lane = tid & 63, wid = tid >> 6;
    const int lm = lane & 15, lg = lane >> 4;
    {
        int c = tid;                    // 256 chunks of 8 bf16 = 16 rows x 128
        int r = c >> 4, off = (c & 15) * 8;
        *(uint4*)&sA[r][off] = *(const uint4*)(V1 + (size_t)(nb + r) * 128 + off);
    }
    __syncthreads();
    // GEMM1: [16][128] @ w1[128][512], gelu -> sH bf16
    {
        f32x4 acc[8];
        #pragma unroll
        for (int i = 0; i < 8; ++i) acc[i] = (f32x4){0.f,0.f,0.f,0.f};
        do_gemm_1m<4, 32, 8>(&sA[0][0], 136, w1p, lane, wid * 8, acc);
        #pragma unroll
        for (int ni = 0; ni < 8; ++ni) {
            int col = (wid * 8 + ni) * 16 + lm;
            float bv = b1[col];
            #pragma unroll
            for (int r = 0; r < 4; ++r)
                sH[lg * 4 + r][col] = __float2bfloat16(gelu_f(acc[ni][r] + bv));
        }
    }
    __syncthreads();
    // GEMM2: [16][512] @ w2[512][128], + V1 residual -> sX f32
    {
        f32x4 acc[2];
        acc[0] = (f32x4){0.f,0.f,0.f,0.f}; acc[1] = (f32x4){0.f,0.f,0.f,0.f};
        do_gemm_1m<16, 8, 2>(&sH[0][0], 520, w2p, lane, wid * 2, acc);
        #pragma unroll
        for (int ni = 0; ni < 2; ++ni) {
            int col = (wid * 2 + ni) * 16 + lm;
            float bv = b2[col];
            #pragma unroll
            for (int r = 0; r < 4; ++r) {
                int row = lg * 4 + r;
                sX[row][col] = __bfloat162float(sA[row][col]) + acc[ni][r] + bv;
            }
        }
    }
    __syncthreads();
    // LN per node
    for (int n = wid; n < 16; n += 4) {
        float a = sX[n][lane], b = sX[n][lane + 64];
        float s = a + b, q = a * a + b * b;
        #pragma unroll
        for (int off = 32; off; off >>= 1) { s += __shfl_xor(s, off); q += __shfl_xor(q, off); }
        float mean = s * (1.f / 128.f);
        float var  = q * (1.f / 128.f) - mean * mean;
        float rs   = rsqrtf(var + 1e-5f);
        size_t base = (size_t)(nb + n) * 128;
        Vout[base + lane]      = (a - mean) * rs * g[lane]      + bta[lane];
        Vout[base + lane + 64] = (b - mean) * rs * g[lane + 64] + bta[lane + 64];
    }
}

// NODE message pass (validated rounds 5-11): occupancy-5, aliased LDS, Yvi buffer.
__global__ __launch_bounds__(256, 5)
void msg_node_kernel(const float* __restrict__ Vf,
                     const float* __restrict__ Ef,
                     const float* __restrict__ maskf,
                     const int*   __restrict__ Kidx,
                     const bf16*  __restrict__ Yvi,
                     const bf16* __restrict__ w1p,
                     const bf16* __restrict__ w2p, const float* __restrict__ b2f,
                     const bf16* __restrict__ w3p, const float* __restrict__ b3f,
                     const float* __restrict__ lng, const float* __restrict__ lnb,
                     const float* __restrict__ Vres,
                     bf16*  __restrict__ V1out)
{
    __shared__ __align__(16) char region0[26112];   // sA[0,25344) ; sH1[0,13056) ; sH2[13056,26112)
    __shared__ float sYvi[128];
    __shared__ float sMask[48];
    __shared__ float sS[128];

    bf16  (*sA)[264]  = reinterpret_cast<bf16(*)[264]>(region0);
    bf16  (*sH1)[136] = reinterpret_cast<bf16(*)[136]>(region0);
    bf16  (*sH2)[136] = reinterpret_cast<bf16(*)[136]>(region0 + 13056);

    const int node = blockIdx.x;
    const int tid  = threadIdx.x;
    const int lane = tid & 63;
    const int wid  = tid >> 6;
    const int z    = node >> 10;
    const int* krow = Kidx + node * KN;

    if (tid < 128) sYvi[tid] = __bfloat162float(Yvi[(size_t)node * 128 + tid]);
    if (tid >= 128 && tid < 128 + KN)
        sMask[tid - 128] = maskf[(size_t)node * KN + (tid - 128)];
    {
        const float* erow0 = Ef + (size_t)node * KN * 128;
        for (int c = tid; c < KN * 32; c += 256) {
            int r = c >> 5;
            int off = (c & 31) * 4;
            int kj = krow[r];
            float4 vj = *(const float4*)(Vf + ((size_t)(z * 1024 + kj)) * 128 + off);
            *(uint2*)&sA[r][off] = pack4(vj.x, vj.y, vj.z, vj.w);
            float4 ee = *(const float4*)(erow0 + r * 128 + off);
            *(uint2*)&sA[r][128 + off] = pack4(ee.x, ee.y, ee.z, ee.w);
        }
    }
    __syncthreads();                                   // B0: sA ready

    const int nt0 = wid * 2;
    const int lm  = lane & 15;
    const int lg  = lane >> 4;
    const f32x4 vzero = {0.f, 0.f, 0.f, 0.f};

    f32x4 acc[3][2];
    #pragma unroll
    for (int mt = 0; mt < 3; ++mt) { acc[mt][0] = vzero; acc[mt][1] = vzero; }
    do_gemm<4, 8>(&sA[0][0], 264, w1p, lane, nt0, acc);
    __syncthreads();                                   // B1: sA reads done (sH1 aliases sA)
    #pragma unroll
    for (int mt = 0; mt < 3; ++mt)
    #pragma unroll
    for (int ni = 0; ni < 2; ++ni) {
        int col = (nt0 + ni) * 16 + lm;
        float yv = sYvi[col];
        #pragma unroll
        for (int r = 0; r < 4; ++r) {
            int row = mt * 16 + lg * 4 + r;
            sH1[row][col] = __float2bfloat16(gelu_f(acc[mt][ni][r] + yv));
        }
    }
    __syncthreads();                                   // B2: sH1 ready

    #pragma unroll
    for (int mt = 0; mt < 3; ++mt) { acc[mt][0] = vzero; acc[mt][1] = vzero; }
    do_gemm<0, 4>(&sH1[0][0], 136, w2p, lane, nt0, acc);
    {
        float bc0 = b2f[nt0 * 16 + lm];
        float bc1 = b2f[(nt0 + 1) * 16 + lm];
        #pragma unroll
        for (int mt = 0; mt < 3; ++mt)
        #pragma unroll
        for (int r = 0; r < 4; ++r) {
            int row = mt * 16 + lg * 4 + r;
            sH2[row][nt0 * 16 + lm]       = __float2bfloat16(gelu_f(acc[mt][0][r] + bc0));
            sH2[row][(nt0 + 1) * 16 + lm] = __float2bfloat16(gelu_f(acc[mt][1][r] + bc1));
        }
    }
    __syncthreads();                                   // B3: sH2 ready

    #pragma unroll
    for (int mt = 0; mt < 3; ++mt) { acc[mt][0] = vzero; acc[mt][1] = vzero; }
    do_gemm<0, 4>(&sH2[0][0], 136, w3p, lane, nt0, acc);
    {
        float bc0 = b3f[nt0 * 16 + lm];
        float bc1 = b3f[(nt0 + 1) * 16 + lm];
        float cs0 = 0.f, cs1 = 0.f;
        #pragma unroll
        for (int mt = 0; mt < 3; ++mt)
        #pragma unroll
        for (int r = 0; r < 4; ++r) {
            float m = sMask[mt * 16 + lg * 4 + r];
            cs0 += (acc[mt][0][r] + bc0) * m;
            cs1 += (acc[mt][1][r] + bc1) * m;
        }
        cs0 += __shfl_xor(cs0, 16); cs0 += __shfl_xor(cs0, 32);
        cs1 += __shfl_xor(cs1, 16); cs1 += __shfl_xor(cs1, 32);
        if (lane < 16) {
            sS[nt0 * 16 + lane]       = cs0;
            sS[(nt0 + 1) * 16 + lane] = cs1;
        }
    }
    __syncthreads();                                   // B5: sS ready

    if (tid < 64) {
        float a = Vres[(size_t)node * 128 + tid]      + sS[tid];
        float b = Vres[(size_t)node * 128 + tid + 64] + sS[tid + 64];
        float s = a + b, q = a * a + b * b;
        #pragma unroll
        for (int off = 32; off; off >>= 1) { s += __shfl_xor(s, off); q += __shfl_xor(q, off); }
        float mean = s * (1.f / 128.f);
        float var  = q * (1.f / 128.f) - mean * mean;
        float rs   = rsqrtf(var + 1e-5f);
        V1out[(size_t)node * 128 + tid] =
            __float2bfloat16((a - mean) * rs * lng[tid] + lnb[tid]);
        V1out[(size_t)node * 128 + tid + 64] =
            __float2bfloat16((b - mean) * rs * lng[tid + 64] + lnb[tid + 64]);
    }
}

// EDGE MLP kernel: GEMM3 epilogue writes Me*mask directly to global f32 (Eout slot).
__global__ __launch_bounds__(256, 5)
void mlp_edge_kernel(const float* __restrict__ Vf,     // V2 (f32) gather source
                     const float* __restrict__ Ef,
                     const float* __restrict__ maskf,
                     const int*   __restrict__ Kidx,
                     const bf16*  __restrict__ Yvi,    // YviE (bf16)
                     const bf16* __restrict__ w1p,
                     const bf16* __restrict__ w2p, const float* __restrict__ b2f,
                     const bf16* __restrict__ w3p, const float* __restrict__ b3f,
                     float* __restrict__ MeOut)        // f32 [4096*48][128] (= Eout slot)
{
    __shared__ __align__(16) char region0[26112];
    __shared__ float sYvi[128];
    __shared__ float sMask[48];

    bf16  (*sA)[264]  = reinterpret_cast<bf16(*)[264]>(region0);
    bf16  (*sH1)[136] = reinterpret_cast<bf16(*)[136]>(region0);
    bf16  (*sH2)[136] = reinterpret_cast<bf16(*)[136]>(region0 + 13056);

    const int node = blockIdx.x;
    const int tid  = threadIdx.x;
    const int lane = tid & 63;
    const int wid  = tid >> 6;
    const int z    = node >> 10;
    const int* krow = Kidx + node * KN;

    if (tid < 128) sYvi[tid] = __bfloat162float(Yvi[(size_t)node * 128 + tid]);
    if (tid >= 128 && tid < 128 + KN)
        sMask[tid - 128] = maskf[(size_t)node * KN + (tid - 128)];
    {
        const float* erow0 = Ef + (size_t)node * KN * 128;
        for (int c = tid; c < KN * 32; c += 256) {
            int r = c >> 5;
            int off = (c & 31) * 4;
            int kj = krow[r];
            float4 vj = *(const float4*)(Vf + ((size_t)(z * 1024 + kj)) * 128 + off);
            *(uint2*)&sA[r][off] = pack4(vj.x, vj.y, vj.z, vj.w);
            float4 ee = *(const float4*)(erow0 + r * 128 + off);
            *(uint2*)&sA[r][128 + off] = pack4(ee.x, ee.y, ee.z, ee.w);
        }
    }
    __syncthreads();                                   // B0

    const int nt0 = wid * 2;
    const int lm  = lane & 15;
    const int lg  = lane >> 4;
    const f32x4 vzero = {0.f, 0.f, 0.f, 0.f};

    f32x4 acc[3][2];
    #pragma unroll
    for (int mt = 0; mt < 3; ++mt) { acc[mt][0] = vzero; acc[mt][1] = vzero; }
    do_gemm<4, 8>(&sA[0][0], 264, w1p, lane, nt0, acc);
    __syncthreads();                                   // B1
    #pragma unroll
    for (int mt = 0; mt < 3; ++mt)
    #pragma unroll
    for (int ni = 0; ni < 2; ++ni) {
        int col = (nt0 + ni) * 16 + lm;
        float yv = sYvi[col];
        #pragma unroll
        for (int r = 0; r < 4; ++r) {
            int row = mt * 16 + lg * 4 + r;
            sH1[row][col] = __float2bfloat16(gelu_f(acc[mt][ni][r] + yv));
        }
    }
    __syncthreads();                                   // B2

    #pragma unroll
    for (int mt = 0; mt < 3; ++mt) { acc[mt][0] = vzero; acc[mt][1] = vzero; }
    do_gemm<0, 4>(&sH1[0][0], 136, w2p, lane, nt0, acc);
    {
        float bc0 = b2f[nt0 * 16 + lm];
        float bc1 = b2f[(nt0 + 1) * 16 + lm];
        #pragma unroll
        for (int mt = 0; mt < 3; ++mt)
        #pragma unroll
        for (int r = 0; r < 4; ++r) {
            int row = mt * 16 + lg * 4 + r;
            sH2[row][nt0 * 16 + lm]       = __float2bfloat16(gelu_f(acc[mt][0][r] + bc0));
            sH2[row][(nt0 + 1) * 16 + lm] = __float2bfloat16(gelu_f(acc[mt][1][r] + bc1));
        }
    }
    __syncthreads();                                   // B3

    #pragma unroll
    for (int mt = 0; mt < 3; ++mt) { acc[mt][0] = vzero; acc[mt][1] = vzero; }
    do_gemm<0, 4>(&sH2[0][0], 136, w3p, lane, nt0, acc);
    {
        float bc0 = b3f[nt0 * 16 + lm];
        float bc1 = b3f[(nt0 + 1) * 16 + lm];
        float* meRow = MeOut + (size_t)node * KN * 128;
        #pragma unroll
        for (int mt = 0; mt < 3; ++mt)
        #pragma unroll
        for (int r = 0; r < 4; ++r) {
            int row = mt * 16 + lg * 4 + r;
            float m = sMask[row];
            meRow[row * 128 + nt0 * 16 + lm]       = (acc[mt][0][r] + bc0) * m;
            meRow[row * 128 + (nt0 + 1) * 16 + lm] = (acc[mt][1][r] + bc1) * m;
        }
    }
}

// EDGE LN kernel: in-place E = LN(E + Me). One wave per row.
__global__ __launch_bounds__(256, 8)
void ln_edge_kernel(const float* __restrict__ Ef,
                    float* __restrict__ Me,
                    const float* __restrict__ g, const float* __restrict__ b)
{
    const int row  = blockIdx.x * 4 + (threadIdx.x >> 6);
    const int lane = threadIdx.x & 63;
    const size_t base = (size_t)row * 128;
    float2 me = ((const float2*)(Me + base))[lane];
    float2 ev = ((const float2*)(Ef + base))[lane];
    float x0 = ev.x + me.x;
    float x1 = ev.y + me.y;
    float s = x0 + x1, q = x0 * x0 + x1 * x1;
    #pragma unroll
    for (int off = 32; off; off >>= 1) { s += __shfl_xor(s, off); q += __shfl_xor(q, off); }
    float mean = s * (1.f / 128.f);
    float var  = q * (1.f / 128.f) - mean * mean;
    float rs   = rsqrtf(var + 1e-5f);
    float2 o;
    o.x = (x0 - mean) * rs * g[2 * lane]     + b[2 * lane];
    o.y = (x1 - mean) * rs * g[2 * lane + 1] + b[2 * lane + 1];
    ((float2*)(Me + base))[lane] = o;
}

extern "C" void kernel_launch(void* const* d_in, const int* in_sizes, int n_in,
                              void* d_out, int out_size, void* d_ws, size_t ws_size,
                              hipStream_t stream) {
    const float* V     = (const float*)d_in[0];
    const float* E     = (const float*)d_in[1];
    const float* emask = (const float*)d_in[2];
    const float* nm_w1 = (const float*)d_in[3];
    const float* nm_b1 = (const float*)d_in[4];
    const float* nm_w2 = (const float*)d_in[5];
    const float* nm_b2 = (const float*)d_in[6];
    const float* nm_w3 = (const float*)d_in[7];
    const float* nm_b3 = (const float*)d_in[8];
    const float* nmn_g = (const float*)d_in[9];
    const float* nmn_b = (const float*)d_in[10];
    const float* ffn_w1 = (const float*)d_in[11];
    const float* ffn_b1 = (const float*)d_in[12];
    const float* ffn_w2 = (const float*)d_in[13];
    const float* ffn_b2 = (const float*)d_in[14];
    const float* fn_g  = (const float*)d_in[15];
    const float* fn_b  = (const float*)d_in[16];
    const float* em_w1 = (const float*)d_in[17];
    const float* em_b1 = (const float*)d_in[18];
    const float* em_w2 = (const float*)d_in[19];
    const float* em_b2 = (const float*)d_in[20];
    const float* em_w3 = (const float*)d_in[21];
    const float* em_b3 = (const float*)d_in[22];
    const float* emn_g = (const float*)d_in[23];
    const float* emn_b = (const float*)d_in[24];
    const int*  K     = (const int*)d_in[25];

    // ws layout (proven footprint):
    //   [0, 327680)            packed msg weights (bf16, 6 segments)
    //   [327680, +1MB)         V1f (bf16) -- reused as YviE after ffn
    //   [327680+1MB, +2MB)     YviN (bf16)
    char* ws = (char*)d_ws;
    bf16* Pall    = (bf16*)(ws);
    bf16* p_nm_w1 = (bf16*)(ws);
    bf16* p_nm_w2 = (bf16*)(ws + 98304);
    bf16* p_nm_w3 = (bf16*)(ws + 131072);
    bf16* p_em_w1 = (bf16*)(ws + 163840);
    bf16* p_em_w2 = (bf16*)(ws + 262144);
    bf16* p_em_w3 = (bf16*)(ws + 294912);
    bf16* V1f  = (bf16*)(ws + 327680);
    bf16* YviE = (bf16*)(ws + 327680);             // reuses V1f slot (dead after ffn)
    bf16* YviN = (bf16*)(ws + 327680 + 1048576);

    float* V2out = (float*)d_out;                 // [4,1024,128] f32
    float* Eout  = (float*)d_out + 524288;        // [4,1024,48,128] f32 (Me staged here first)

    // ffn packed weights staged in the TAIL of Eout: written by pack_ffn, read by
    // ffn_mfma, then fully overwritten by mlp_edge's Me write (sequential stream).
    // total d_out floats = 25690112; two 65536-elem bf16 arrays = 65536 floats.
    bf16* fw1p = (bf16*)((float*)d_out + 25690112 - 65536);
    bf16* fw2p = (bf16*)((float*)d_out + 25690112 - 32768);

    pack_all_kernel<<<640, 256, 0, stream>>>(nm_w1, nm_w2, nm_w3, em_w1, em_w2, em_w3, Pall);
    pack_ffn_kernel<<<512, 256, 0, stream>>>(ffn_w1, ffn_w2, fw1p, fw2p);

    yvi_mfma_kernel<<<ZN / 16, 256, 0, stream>>>(V, p_nm_w1, nm_b1, YviN);

    msg_node_kernel<<<ZN, 256, 0, stream>>>(
        V, E, emask, K, YviN,
        p_nm_w1, p_nm_w2, nm_b2, p_nm_w3, nm_b3,
        nmn_g, nmn_b, V, V1f);

    ffn_mfma_kernel<<<ZN / 16, 256, 0, stream>>>(
        V1f, fw1p, ffn_b1, fw2p, ffn_b2, fn_g, fn_b, V2out);

    yvi_mfma_kernel<<<ZN / 16, 256, 0, stream>>>(V2out, p_em_w1, em_b1, YviE);

    mlp_edge_kernel<<<ZN, 256, 0, stream>>>(
        V2out, E, emask, K, YviE,
        p_em_w1, p_em_w2, em_b2, p_em_w3, em_b3,
        Eout);

    ln_edge_kernel<<<ZN * KN / 4, 256, 0, stream>>>(E, Eout, emn_g, emn_b);
}

// Round 13
// 171.558 us; speedup vs baseline: 2.3420x; 1.1215x over previous
//
#include <hip/hip_runtime.h>
#include <hip/hip_bf16.h>

using bf16 = __hip_bfloat16;
typedef __attribute__((ext_vector_type(8))) short short8;
typedef __attribute__((ext_vector_type(4))) float f32x4;

#define ZN 4096
#define KN 48

__device__ __forceinline__ float gelu_f(float x) {
    return 0.5f * x * (1.0f + erff(x * 0.70710678118654752440f));
}

__device__ __forceinline__ uint2 pack4(float a, float b, float c, float d) {
    union { bf16 h[4]; uint2 u; } t;
    t.h[0] = __float2bfloat16(a); t.h[1] = __float2bfloat16(b);
    t.h[2] = __float2bfloat16(c); t.h[3] = __float2bfloat16(d);
    return t.u;
}

// Pack all six msg W[K][128] (row-major f32) into one contiguous bf16 MFMA B-fragment buffer.
__global__ void pack_all_kernel(const float* __restrict__ nm1, const float* __restrict__ nm2,
                                const float* __restrict__ nm3, const float* __restrict__ em1,
                                const float* __restrict__ em2, const float* __restrict__ em3,
                                bf16* __restrict__ P) {
    int idx = blockIdx.x * 256 + threadIdx.x;          // 0 .. 163839
    const float* W; int local;
    if      (idx <  49152) { W = nm1; local = idx;          }
    else if (idx <  65536) { W = nm2; local = idx -  49152; }
    else if (idx <  81920) { W = nm3; local = idx -  65536; }
    else if (idx < 131072) { W = em1; local = idx -  81920; }
    else if (idx < 147456) { W = em2; local = idx - 131072; }
    else                   { W = em3; local = idx - 147456; }
    int j    = local & 7;
    int lane = (local >> 3) & 63;
    int nt   = (local >> 9) & 7;
    int ks   = local >> 12;
    int k = ks * 32 + ((lane >> 4) << 3) + j;
    int n = nt * 16 + (lane & 15);
    P[idx] = __float2bfloat16(W[k * 128 + n]);
}

// Pack ffn weights: w1 [128][512] (NT=32, ks 0..3), w2 [512][128] (NT=8, ks 0..15).
__global__ void pack_ffn_kernel(const float* __restrict__ w1, const float* __restrict__ w2,
                                bf16* __restrict__ P1, bf16* __restrict__ P2) {
    int idx = blockIdx.x * 256 + threadIdx.x;          // 0 .. 131071
    if (idx < 65536) {
        int local = idx;
        int j = local & 7, lane = (local >> 3) & 63, nt = (local >> 9) & 31, ks = local >> 14;
        int k = ks * 32 + ((lane >> 4) << 3) + j;
        int n = nt * 16 + (lane & 15);
        P1[local] = __float2bfloat16(w1[k * 512 + n]);
    } else {
        int local = idx - 65536;
        int j = local & 7, lane = (local >> 3) & 63, nt = (local >> 9) & 7, ks = local >> 12;
        int k = ks * 32 + ((lane >> 4) << 3) + j;
        int n = nt * 16 + (lane & 15);
        P2[local] = __float2bfloat16(w2[k * 128 + n]);
    }
}

// 3-Mtile GEMM stage (msg kernels): A [48][ldA] bf16 in LDS, B packed (NT=8).
template<int KSBEG, int NSTEPS>
__device__ __forceinline__ void do_gemm(const bf16* A, int ldA, const bf16* Bp,
                                        int lane, int nt0, f32x4 acc[3][2]) {
    #pragma unroll
    for (int s = 0; s < NSTEPS; ++s) {
        int ks = KSBEG + s;
        short8 b0 = *(const short8*)(Bp + (((ks * 8 + nt0) * 64 + lane) << 3));
        short8 b1 = *(const short8*)(Bp + (((ks * 8 + nt0 + 1) * 64 + lane) << 3));
        int kcol = s * 32 + ((lane >> 4) << 3);
        #pragma unroll
        for (int mt = 0; mt < 3; ++mt) {
            short8 a = *(const short8*)(A + (mt * 16 + (lane & 15)) * ldA + kcol);
            acc[mt][0] = __builtin_amdgcn_mfma_f32_16x16x32_bf16(a, b0, acc[mt][0], 0, 0, 0);
            acc[mt][1] = __builtin_amdgcn_mfma_f32_16x16x32_bf16(a, b1, acc[mt][1], 0, 0, 0);
        }
    }
}

// 1-Mtile GEMM stage: A [16][ldA] bf16 in LDS, B packed with NT n-tiles per ks.
template<int NSTEPS, int NT, int NACC>
__device__ __forceinline__ void do_gemm_1m(const bf16* A, int ldA, const bf16* Bp,
                                           int lane, int nt0, f32x4 acc[NACC]) {
    #pragma unroll
    for (int s = 0; s < NSTEPS; ++s) {
        int kcol = s * 32 + ((lane >> 4) << 3);
        short8 a = *(const short8*)(A + (lane & 15) * ldA + kcol);
        #pragma unroll
        for (int ni = 0; ni < NACC; ++ni) {
            short8 b = *(const short8*)(Bp + (((s * NT + nt0 + ni) * 64 + lane) << 3));
            acc[ni] = __builtin_amdgcn_mfma_f32_16x16x32_bf16(a, b, acc[ni], 0, 0, 0);
        }
    }
}

// Yvi[n][:] = b1 + Vsrc[n]@w1[0:128,:] via MFMA, using ks 0..3 of the packed msg w1.
__global__ __launch_bounds__(256, 4)
void yvi_mfma_kernel(const float* __restrict__ Vsrc, const bf16* __restrict__ w1p,
                     const float* __restrict__ b1f, bf16* __restrict__ out)
{
    __shared__ __align__(16) bf16 sA[16][136];
    const int nb  = blockIdx.x * 16;
    const int tid = threadIdx.x;
    const int lane = tid & 63, wid = tid >> 6;
    for (int c = tid; c < 16 * 32; c += 256) {
        int r = c >> 5, off = (c & 31) * 4;
        float4 v = *(const float4*)(Vsrc + (size_t)(nb + r) * 128 + off);
        *(uint2*)&sA[r][off] = pack4(v.x, v.y, v.z, v.w);
    }
    __syncthreads();
    const int nt0 = wid * 2;
    f32x4 acc[2];
    acc[0] = (f32x4){0.f,0.f,0.f,0.f}; acc[1] = (f32x4){0.f,0.f,0.f,0.f};
    do_gemm_1m<4, 8, 2>(&sA[0][0], 136, w1p, lane, nt0, acc);
    const int lm = lane & 15, lg = lane >> 4;
    #pragma unroll
    for (int ni = 0; ni < 2; ++ni) {
        int col = (nt0 + ni) * 16 + lm;
        float bv = b1f[col];
        #pragma unroll
        for (int r = 0; r < 4; ++r)
            out[(size_t)(nb + lg * 4 + r) * 128 + col] = __float2bfloat16(acc[ni][r] + bv);
    }
}

// FFN via MFMA: V2 = LN(V1 + gelu(V1@w1+b1)@w2+b2), 16 nodes/block.
__global__ __launch_bounds__(256, 2)
void ffn_mfma_kernel(const bf16* __restrict__ V1,
                     const bf16* __restrict__ w1p, const float* __restrict__ b1,
                     const bf16* __restrict__ w2p, const float* __restrict__ b2,
                     const float* __restrict__ g, const float* __restrict__ bta,
                     float* __restrict__ Vout)
{
    __shared__ __align__(16) bf16 sA[16][136];
    __shared__ __align__(16) bf16 sH[16][520];
    __shared__ float sX[16][132];
    const int nb  = blockIdx.x * 16;
    const int tid = threadIdx.x;
    const int lane = tid & 63, wid = tid >> 6;
    const int lm = lane & 15, lg = lane >> 4;
    {
        int c = tid;                    // 256 chunks of 8 bf16 = 16 rows x 128
        int r = c >> 4, off = (c & 15) * 8;
        *(uint4*)&sA[r][off] = *(const uint4*)(V1 + (size_t)(nb + r) * 128 + off);
    }
    __syncthreads();
    {
        f32x4 acc[8];
        #pragma unroll
        for (int i = 0; i < 8; ++i) acc[i] = (f32x4){0.f,0.f,0.f,0.f};
        do_gemm_1m<4, 32, 8>(&sA[0][0], 136, w1p, lane, wid * 8, acc);
        #pragma unroll
        for (int ni = 0; ni < 8; ++ni) {
            int col = (wid * 8 + ni) * 16 + lm;
            float bv = b1[col];
            #pragma unroll
            for (int r = 0; r < 4; ++r)
                sH[lg * 4 + r][col] = __float2bfloat16(gelu_f(acc[ni][r] + bv));
        }
    }
    __syncthreads();
    {
        f32x4 acc[2];
        acc[0] = (f32x4){0.f,0.f,0.f,0.f}; acc[1] = (f32x4){0.f,0.f,0.f,0.f};
        do_gemm_1m<16, 8, 2>(&sH[0][0], 520, w2p, lane, wid * 2, acc);
        #pragma unroll
        for (int ni = 0; ni < 2; ++ni) {
            int col = (wid * 2 + ni) * 16 + lm;
            float bv = b2[col];
            #pragma unroll
            for (int r = 0; r < 4; ++r) {
                int row = lg * 4 + r;
                sX[row][col] = __bfloat162float(sA[row][col]) + acc[ni][r] + bv;
            }
        }
    }
    __syncthreads();
    for (int n = wid; n < 16; n += 4) {
        float a = sX[n][lane], b = sX[n][lane + 64];
        float s = a + b, q = a * a + b * b;
        #pragma unroll
        for (int off = 32; off; off >>= 1) { s += __shfl_xor(s, off); q += __shfl_xor(q, off); }
        float mean = s * (1.f / 128.f);
        float var  = q * (1.f / 128.f) - mean * mean;
        float rs   = rsqrtf(var + 1e-5f);
        size_t base = (size_t)(nb + n) * 128;
        Vout[base + lane]      = (a - mean) * rs * g[lane]      + bta[lane];
        Vout[base + lane + 64] = (b - mean) * rs * g[lane + 64] + bta[lane + 64];
    }
}

// NODE message pass (validated rounds 5-12): occupancy-5, aliased LDS, Yvi buffer.
__global__ __launch_bounds__(256, 5)
void msg_node_kernel(const float* __restrict__ Vf,
                     const float* __restrict__ Ef,
                     const float* __restrict__ maskf,
                     const int*   __restrict__ Kidx,
                     const bf16*  __restrict__ Yvi,
                     const bf16* __restrict__ w1p,
                     const bf16* __restrict__ w2p, const float* __restrict__ b2f,
                     const bf16* __restrict__ w3p, const float* __restrict__ b3f,
                     const float* __restrict__ lng, const float* __restrict__ lnb,
                     const float* __restrict__ Vres,
                     bf16*  __restrict__ V1out)
{
    __shared__ __align__(16) char region0[26112];   // sA[0,25344) ; sH1[0,13056) ; sH2[13056,26112)
    __shared__ float sYvi[128];
    __shared__ float sMask[48];
    __shared__ float sS[128];

    bf16  (*sA)[264]  = reinterpret_cast<bf16(*)[264]>(region0);
    bf16  (*sH1)[136] = reinterpret_cast<bf16(*)[136]>(region0);
    bf16  (*sH2)[136] = reinterpret_cast<bf16(*)[136]>(region0 + 13056);

    const int node = blockIdx.x;
    const int tid  = threadIdx.x;
    const int lane = tid & 63;
    const int wid  = tid >> 6;
    const int z    = node >> 10;
    const int* krow = Kidx + node * KN;

    if (tid < 128) sYvi[tid] = __bfloat162float(Yvi[(size_t)node * 128 + tid]);
    if (tid >= 128 && tid < 128 + KN)
        sMask[tid - 128] = maskf[(size_t)node * KN + (tid - 128)];
    {
        const float* erow0 = Ef + (size_t)node * KN * 128;
        for (int c = tid; c < KN * 32; c += 256) {
            int r = c >> 5;
            int off = (c & 31) * 4;
            int kj = krow[r];
            float4 vj = *(const float4*)(Vf + ((size_t)(z * 1024 + kj)) * 128 + off);
            *(uint2*)&sA[r][off] = pack4(vj.x, vj.y, vj.z, vj.w);
            float4 ee = *(const float4*)(erow0 + r * 128 + off);
            *(uint2*)&sA[r][128 + off] = pack4(ee.x, ee.y, ee.z, ee.w);
        }
    }
    __syncthreads();                                   // B0: sA ready

    const int nt0 = wid * 2;
    const int lm  = lane & 15;
    const int lg  = lane >> 4;
    const f32x4 vzero = {0.f, 0.f, 0.f, 0.f};

    f32x4 acc[3][2];
    #pragma unroll
    for (int mt = 0; mt < 3; ++mt) { acc[mt][0] = vzero; acc[mt][1] = vzero; }
    do_gemm<4, 8>(&sA[0][0], 264, w1p, lane, nt0, acc);
    __syncthreads();                                   // B1: sA reads done (sH1 aliases sA)
    #pragma unroll
    for (int mt = 0; mt < 3; ++mt)
    #pragma unroll
    for (int ni = 0; ni < 2; ++ni) {
        int col = (nt0 + ni) * 16 + lm;
        float yv = sYvi[col];
        #pragma unroll
        for (int r = 0; r < 4; ++r) {
            int row = mt * 16 + lg * 4 + r;
            sH1[row][col] = __float2bfloat16(gelu_f(acc[mt][ni][r] + yv));
        }
    }
    __syncthreads();                                   // B2: sH1 ready

    #pragma unroll
    for (int mt = 0; mt < 3; ++mt) { acc[mt][0] = vzero; acc[mt][1] = vzero; }
    do_gemm<0, 4>(&sH1[0][0], 136, w2p, lane, nt0, acc);
    {
        float bc0 = b2f[nt0 * 16 + lm];
        float bc1 = b2f[(nt0 + 1) * 16 + lm];
        #pragma unroll
        for (int mt = 0; mt < 3; ++mt)
        #pragma unroll
        for (int r = 0; r < 4; ++r) {
            int row = mt * 16 + lg * 4 + r;
            sH2[row][nt0 * 16 + lm]       = __float2bfloat16(gelu_f(acc[mt][0][r] + bc0));
            sH2[row][(nt0 + 1) * 16 + lm] = __float2bfloat16(gelu_f(acc[mt][1][r] + bc1));
        }
    }
    __syncthreads();                                   // B3: sH2 ready

    #pragma unroll
    for (int mt = 0; mt < 3; ++mt) { acc[mt][0] = vzero; acc[mt][1] = vzero; }
    do_gemm<0, 4>(&sH2[0][0], 136, w3p, lane, nt0, acc);
    {
        float bc0 = b3f[nt0 * 16 + lm];
        float bc1 = b3f[(nt0 + 1) * 16 + lm];
        float cs0 = 0.f, cs1 = 0.f;
        #pragma unroll
        for (int mt = 0; mt < 3; ++mt)
        #pragma unroll
        for (int r = 0; r < 4; ++r) {
            float m = sMask[mt * 16 + lg * 4 + r];
            cs0 += (acc[mt][0][r] + bc0) * m;
            cs1 += (acc[mt][1][r] + bc1) * m;
        }
        cs0 += __shfl_xor(cs0, 16); cs0 += __shfl_xor(cs0, 32);
        cs1 += __shfl_xor(cs1, 16); cs1 += __shfl_xor(cs1, 32);
        if (lane < 16) {
            sS[nt0 * 16 + lane]       = cs0;
            sS[(nt0 + 1) * 16 + lane] = cs1;
        }
    }
    __syncthreads();                                   // B5: sS ready

    if (tid < 64) {
        float a = Vres[(size_t)node * 128 + tid]      + sS[tid];
        float b = Vres[(size_t)node * 128 + tid + 64] + sS[tid + 64];
        float s = a + b, q = a * a + b * b;
        #pragma unroll
        for (int off = 32; off; off >>= 1) { s += __shfl_xor(s, off); q += __shfl_xor(q, off); }
        float mean = s * (1.f / 128.f);
        float var  = q * (1.f / 128.f) - mean * mean;
        float rs   = rsqrtf(var + 1e-5f);
        V1out[(size_t)node * 128 + tid] =
            __float2bfloat16((a - mean) * rs * lng[tid] + lnb[tid]);
        V1out[(size_t)node * 128 + tid + 64] =
            __float2bfloat16((b - mean) * rs * lng[tid + 64] + lnb[tid + 64]);
    }
}

// EDGE MLP kernel with FUSED LN: x = E + Me*mask kept in registers; only 1.5 KB of
// per-row partial sums (sPart, dedicated array — the proven sS mechanism) crosses
// waves. Writes final E directly. No full-Me LDS buffer (the R5-R10 curse).
__global__ __launch_bounds__(256, 5)
void mlp_edge_kernel(const float* __restrict__ Vf,     // V2 (f32) gather source
                     const float* __restrict__ Ef,
                     const float* __restrict__ maskf,
                     const int*   __restrict__ Kidx,
                     const bf16*  __restrict__ Yvi,    // YviE (bf16)
                     const bf16* __restrict__ w1p,
                     const bf16* __restrict__ w2p, const float* __restrict__ b2f,
                     const bf16* __restrict__ w3p, const float* __restrict__ b3f,
                     const float* __restrict__ lng, const float* __restrict__ lnb,
                     float* __restrict__ Eout)         // f32 final E
{
    __shared__ __align__(16) char region0[26112];
    __shared__ float sYvi[128];
    __shared__ float sMask[48];
    __shared__ float sPart[48][4][2];                  // per-row {sum, sumsq} per wave

    bf16  (*sA)[264]  = reinterpret_cast<bf16(*)[264]>(region0);
    bf16  (*sH1)[136] = reinterpret_cast<bf16(*)[136]>(region0);
    bf16  (*sH2)[136] = reinterpret_cast<bf16(*)[136]>(region0 + 13056);

    const int node = blockIdx.x;
    const int tid  = threadIdx.x;
    const int lane = tid & 63;
    const int wid  = tid >> 6;
    const int z    = node >> 10;
    const int* krow = Kidx + node * KN;

    if (tid < 128) sYvi[tid] = __bfloat162float(Yvi[(size_t)node * 128 + tid]);
    if (tid >= 128 && tid < 128 + KN)
        sMask[tid - 128] = maskf[(size_t)node * KN + (tid - 128)];
    {
        const float* erow0 = Ef + (size_t)node * KN * 128;
        for (int c = tid; c < KN * 32; c += 256) {
            int r = c >> 5;
            int off = (c & 31) * 4;
            int kj = krow[r];
            float4 vj = *(const float4*)(Vf + ((size_t)(z * 1024 + kj)) * 128 + off);
            *(uint2*)&sA[r][off] = pack4(vj.x, vj.y, vj.z, vj.w);
            float4 ee = *(const float4*)(erow0 + r * 128 + off);
            *(uint2*)&sA[r][128 + off] = pack4(ee.x, ee.y, ee.z, ee.w);
        }
    }
    __syncthreads();                                   // B0

    const int nt0 = wid * 2;
    const int lm  = lane & 15;
    const int lg  = lane >> 4;
    const f32x4 vzero = {0.f, 0.f, 0.f, 0.f};

    f32x4 acc[3][2];
    #pragma unroll
    for (int mt = 0; mt < 3; ++mt) { acc[mt][0] = vzero; acc[mt][1] = vzero; }
    do_gemm<4, 8>(&sA[0][0], 264, w1p, lane, nt0, acc);
    __syncthreads();                                   // B1
    #pragma unroll
    for (int mt = 0; mt < 3; ++mt)
    #pragma unroll
    for (int ni = 0; ni < 2; ++ni) {
        int col = (nt0 + ni) * 16 + lm;
        float yv = sYvi[col];
        #pragma unroll
        for (int r = 0; r < 4; ++r) {
            int row = mt * 16 + lg * 4 + r;
            sH1[row][col] = __float2bfloat16(gelu_f(acc[mt][ni][r] + yv));
        }
    }
    __syncthreads();                                   // B2

    #pragma unroll
    for (int mt = 0; mt < 3; ++mt) { acc[mt][0] = vzero; acc[mt][1] = vzero; }
    do_gemm<0, 4>(&sH1[0][0], 136, w2p, lane, nt0, acc);
    {
        float bc0 = b2f[nt0 * 16 + lm];
        float bc1 = b2f[(nt0 + 1) * 16 + lm];
        #pragma unroll
        for (int mt = 0; mt < 3; ++mt)
        #pragma unroll
        for (int r = 0; r < 4; ++r) {
            int row = mt * 16 + lg * 4 + r;
            sH2[row][nt0 * 16 + lm]       = __float2bfloat16(gelu_f(acc[mt][0][r] + bc0));
            sH2[row][(nt0 + 1) * 16 + lm] = __float2bfloat16(gelu_f(acc[mt][1][r] + bc1));
        }
    }
    __syncthreads();                                   // B3

    #pragma unroll
    for (int mt = 0; mt < 3; ++mt) { acc[mt][0] = vzero; acc[mt][1] = vzero; }
    do_gemm<0, 4>(&sH2[0][0], 136, w3p, lane, nt0, acc);

    // ---- fused epilogue: x = E + Me*mask (registers), per-row partial sums to sPart ----
    float xv[3][4][2];
    {
        float bc0 = b3f[nt0 * 16 + lm];
        float bc1 = b3f[(nt0 + 1) * 16 + lm];
        const float* erow0 = Ef + (size_t)node * KN * 128;
        #pragma unroll
        for (int mt = 0; mt < 3; ++mt)
        #pragma unroll
        for (int r = 0; r < 4; ++r) {
            int row = mt * 16 + lg * 4 + r;
            float m = sMask[row];
            float x0 = erow0[row * 128 + nt0 * 16 + lm]       + (acc[mt][0][r] + bc0) * m;
            float x1 = erow0[row * 128 + (nt0 + 1) * 16 + lm] + (acc[mt][1][r] + bc1) * m;
            xv[mt][r][0] = x0; xv[mt][r][1] = x1;
            float s = x0 + x1, q = x0 * x0 + x1 * x1;
            s += __shfl_xor(s, 1); q += __shfl_xor(q, 1);
            s += __shfl_xor(s, 2); q += __shfl_xor(q, 2);
            s += __shfl_xor(s, 4); q += __shfl_xor(q, 4);
            s += __shfl_xor(s, 8); q += __shfl_xor(q, 8);
            if (lm == 0) { sPart[row][wid][0] = s; sPart[row][wid][1] = q; }
        }
    }
    __syncthreads();                                   // B4: sPart ready

    {
        float g0 = lng[nt0 * 16 + lm],       b0 = lnb[nt0 * 16 + lm];
        float g1 = lng[(nt0 + 1) * 16 + lm], b1 = lnb[(nt0 + 1) * 16 + lm];
        float* orow0 = Eout + (size_t)node * KN * 128;
        #pragma unroll
        for (int mt = 0; mt < 3; ++mt)
        #pragma unroll
        for (int r = 0; r < 4; ++r) {
            int row = mt * 16 + lg * 4 + r;
            float s = sPart[row][0][0] + sPart[row][1][0] + sPart[row][2][0] + sPart[row][3][0];
            float q = sPart[row][0][1] + sPart[row][1][1] + sPart[row][2][1] + sPart[row][3][1];
            float mean = s * (1.f / 128.f);
            float var  = q * (1.f / 128.f) - mean * mean;
            float rs   = rsqrtf(var + 1e-5f);
            orow0[row * 128 + nt0 * 16 + lm]       = (xv[mt][r][0] - mean) * rs * g0 + b0;
            orow0[row * 128 + (nt0 + 1) * 16 + lm] = (xv[mt][r][1] - mean) * rs * g1 + b1;
        }
    }
}

extern "C" void kernel_launch(void* const* d_in, const int* in_sizes, int n_in,
                              void* d_out, int out_size, void* d_ws, size_t ws_size,
                              hipStream_t stream) {
    const float* V     = (const float*)d_in[0];
    const float* E     = (const float*)d_in[1];
    const float* emask = (const float*)d_in[2];
    const float* nm_w1 = (const float*)d_in[3];
    const float* nm_b1 = (const float*)d_in[4];
    const float* nm_w2 = (const float*)d_in[5];
    const float* nm_b2 = (const float*)d_in[6];
    const float* nm_w3 = (const float*)d_in[7];
    const float* nm_b3 = (const float*)d_in[8];
    const float* nmn_g = (const float*)d_in[9];
    const float* nmn_b = (const float*)d_in[10];
    const float* ffn_w1 = (const float*)d_in[11];
    const float* ffn_b1 = (const float*)d_in[12];
    const float* ffn_w2 = (const float*)d_in[13];
    const float* ffn_b2 = (const float*)d_in[14];
    const float* fn_g  = (const float*)d_in[15];
    const float* fn_b  = (const float*)d_in[16];
    const float* em_w1 = (const float*)d_in[17];
    const float* em_b1 = (const float*)d_in[18];
    const float* em_w2 = (const float*)d_in[19];
    const float* em_b2 = (const float*)d_in[20];
    const float* em_w3 = (const float*)d_in[21];
    const float* em_b3 = (const float*)d_in[22];
    const float* emn_g = (const float*)d_in[23];
    const float* emn_b = (const float*)d_in[24];
    const int*  K     = (const int*)d_in[25];

    // ws layout (proven footprint):
    //   [0, 327680)            packed msg weights (bf16, 6 segments)
    //   [327680, +1MB)         V1f (bf16) -- reused as YviE after ffn
    //   [327680+1MB, +2MB)     YviN (bf16)
    char* ws = (char*)d_ws;
    bf16* Pall    = (bf16*)(ws);
    bf16* p_nm_w1 = (bf16*)(ws);
    bf16* p_nm_w2 = (bf16*)(ws + 98304);
    bf16* p_nm_w3 = (bf16*)(ws + 131072);
    bf16* p_em_w1 = (bf16*)(ws + 163840);
    bf16* p_em_w2 = (bf16*)(ws + 262144);
    bf16* p_em_w3 = (bf16*)(ws + 294912);
    bf16* V1f  = (bf16*)(ws + 327680);
    bf16* YviE = (bf16*)(ws + 327680);             // reuses V1f slot (dead after ffn)
    bf16* YviN = (bf16*)(ws + 327680 + 1048576);

    float* V2out = (float*)d_out;                 // [4,1024,128] f32
    float* Eout  = (float*)d_out + 524288;        // [4,1024,48,128] f32

    // ffn packed weights staged in the TAIL of Eout: written by pack_ffn, read by
    // ffn_mfma, then overwritten by mlp_edge's final-E write.
    bf16* fw1p = (bf16*)((float*)d_out + 25690112 - 65536);
    bf16* fw2p = (bf16*)((float*)d_out + 25690112 - 32768);

    pack_all_kernel<<<640, 256, 0, stream>>>(nm_w1, nm_w2, nm_w3, em_w1, em_w2, em_w3, Pall);
    pack_ffn_kernel<<<512, 256, 0, stream>>>(ffn_w1, ffn_w2, fw1p, fw2p);

    yvi_mfma_kernel<<<ZN / 16, 256, 0, stream>>>(V, p_nm_w1, nm_b1, YviN);

    msg_node_kernel<<<ZN, 256, 0, stream>>>(
        V, E, emask, K, YviN,
        p_nm_w1, p_nm_w2, nm_b2, p_nm_w3, nm_b3,
        nmn_g, nmn_b, V, V1f);

    ffn_mfma_kernel<<<ZN / 16, 256, 0, stream>>>(
        V1f, fw1p, ffn_b1, fw2p, ffn_b2, fn_g, fn_b, V2out);

    yvi_mfma_kernel<<<ZN / 16, 256, 0, stream>>>(V2out, p_em_w1, em_b1, YviE);

    mlp_edge_kernel<<<ZN, 256, 0, stream>>>(
        V2out, E, emask, K, YviE,
        p_em_w1, p_em_w2, em_b2, p_em_w3, em_b3,
        emn_g, emn_b, Eout);
}

// Round 14
// 169.353 us; speedup vs baseline: 2.3725x; 1.0130x over previous
//
#include <hip/hip_runtime.h>
#include <hip/hip_bf16.h>

using bf16 = __hip_bfloat16;
typedef __attribute__((ext_vector_type(8))) short short8;
typedef __attribute__((ext_vector_type(4))) float f32x4;

#define ZN 4096
#define KN 48

// tanh-form GELU: 0.5x(1+tanh(sqrt(2/pi)(x+0.044715x^3))) == x*sigmoid(1.595769x+0.0713548x^3)
// max |diff vs exact erf-gelu| ~= 3e-4 — 10x below the bf16 rounding applied right after.
__device__ __forceinline__ float gelu_f(float x) {
    float t = x * x;
    float z = x * fmaf(0.07135481627f, t, 1.595769122f);
    return x / (1.0f + __expf(-z));
}

__device__ __forceinline__ uint2 pack4(float a, float b, float c, float d) {
    union { bf16 h[4]; uint2 u; } t;
    t.h[0] = __float2bfloat16(a); t.h[1] = __float2bfloat16(b);
    t.h[2] = __float2bfloat16(c); t.h[3] = __float2bfloat16(d);
    return t.u;
}

// Pack all six msg W[K][128] (row-major f32) into one contiguous bf16 MFMA B-fragment buffer.
__global__ void pack_all_kernel(const float* __restrict__ nm1, const float* __restrict__ nm2,
                                const float* __restrict__ nm3, const float* __restrict__ em1,
                                const float* __restrict__ em2, const float* __restrict__ em3,
                                bf16* __restrict__ P) {
    int idx = blockIdx.x * 256 + threadIdx.x;          // 0 .. 163839
    const float* W; int local;
    if      (idx <  49152) { W = nm1; local = idx;          }
    else if (idx <  65536) { W = nm2; local = idx -  49152; }
    else if (idx <  81920) { W = nm3; local = idx -  65536; }
    else if (idx < 131072) { W = em1; local = idx -  81920; }
    else if (idx < 147456) { W = em2; local = idx - 131072; }
    else                   { W = em3; local = idx - 147456; }
    int j    = local & 7;
    int lane = (local >> 3) & 63;
    int nt   = (local >> 9) & 7;
    int ks   = local >> 12;
    int k = ks * 32 + ((lane >> 4) << 3) + j;
    int n = nt * 16 + (lane & 15);
    P[idx] = __float2bfloat16(W[k * 128 + n]);
}

// Pack ffn weights: w1 [128][512] (NT=32, ks 0..3), w2 [512][128] (NT=8, ks 0..15).
__global__ void pack_ffn_kernel(const float* __restrict__ w1, const float* __restrict__ w2,
                                bf16* __restrict__ P1, bf16* __restrict__ P2) {
    int idx = blockIdx.x * 256 + threadIdx.x;          // 0 .. 131071
    if (idx < 65536) {
        int local = idx;
        int j = local & 7, lane = (local >> 3) & 63, nt = (local >> 9) & 31, ks = local >> 14;
        int k = ks * 32 + ((lane >> 4) << 3) + j;
        int n = nt * 16 + (lane & 15);
        P1[local] = __float2bfloat16(w1[k * 512 + n]);
    } else {
        int local = idx - 65536;
        int j = local & 7, lane = (local >> 3) & 63, nt = (local >> 9) & 7, ks = local >> 12;
        int k = ks * 32 + ((lane >> 4) << 3) + j;
        int n = nt * 16 + (lane & 15);
        P2[local] = __float2bfloat16(w2[k * 128 + n]);
    }
}

// 3-Mtile GEMM stage (msg kernels): A [48][ldA] bf16 in LDS, B packed (NT=8).
template<int KSBEG, int NSTEPS>
__device__ __forceinline__ void do_gemm(const bf16* A, int ldA, const bf16* Bp,
                                        int lane, int nt0, f32x4 acc[3][2]) {
    #pragma unroll
    for (int s = 0; s < NSTEPS; ++s) {
        int ks = KSBEG + s;
        short8 b0 = *(const short8*)(Bp + (((ks * 8 + nt0) * 64 + lane) << 3));
        short8 b1 = *(const short8*)(Bp + (((ks * 8 + nt0 + 1) * 64 + lane) << 3));
        int kcol = s * 32 + ((lane >> 4) << 3);
        #pragma unroll
        for (int mt = 0; mt < 3; ++mt) {
            short8 a = *(const short8*)(A + (mt * 16 + (lane & 15)) * ldA + kcol);
            acc[mt][0] = __builtin_amdgcn_mfma_f32_16x16x32_bf16(a, b0, acc[mt][0], 0, 0, 0);
            acc[mt][1] = __builtin_amdgcn_mfma_f32_16x16x32_bf16(a, b1, acc[mt][1], 0, 0, 0);
        }
    }
}

// 1-Mtile GEMM stage: A [16][ldA] bf16 in LDS, B packed with NT n-tiles per ks.
template<int NSTEPS, int NT, int NACC>
__device__ __forceinline__ void do_gemm_1m(const bf16* A, int ldA, const bf16* Bp,
                                           int lane, int nt0, f32x4 acc[NACC]) {
    #pragma unroll
    for (int s = 0; s < NSTEPS; ++s) {
        int kcol = s * 32 + ((lane >> 4) << 3);
        short8 a = *(const short8*)(A + (lane & 15) * ldA + kcol);
        #pragma unroll
        for (int ni = 0; ni < NACC; ++ni) {
            short8 b = *(const short8*)(Bp + (((s * NT + nt0 + ni) * 64 + lane) << 3));
            acc[ni] = __builtin_amdgcn_mfma_f32_16x16x32_bf16(a, b, acc[ni], 0, 0, 0);
        }
    }
}

// Yvi[n][:] = b1 + Vsrc[n]@w1[0:128,:] via MFMA, using ks 0..3 of the packed msg w1.
__global__ __launch_bounds__(256, 4)
void yvi_mfma_kernel(const float* __restrict__ Vsrc, const bf16* __restrict__ w1p,
                     const float* __restrict__ b1f, bf16* __restrict__ out)
{
    __shared__ __align__(16) bf16 sA[16][136];
    const int nb  = blockIdx.x * 16;
    const int tid = threadIdx.x;
    const int lane = tid & 63, wid = tid >> 6;
    for (int c = tid; c < 16 * 32; c += 256) {
        int r = c >> 5, off = (c & 31) * 4;
        float4 v = *(const float4*)(Vsrc + (size_t)(nb + r) * 128 + off);
        *(uint2*)&sA[r][off] = pack4(v.x, v.y, v.z, v.w);
    }
    __syncthreads();
    const int nt0 = wid * 2;
    f32x4 acc[2];
    acc[0] = (f32x4){0.f,0.f,0.f,0.f}; acc[1] = (f32x4){0.f,0.f,0.f,0.f};
    do_gemm_1m<4, 8, 2>(&sA[0][0], 136, w1p, lane, nt0, acc);
    const int lm = lane & 15, lg = lane >> 4;
    #pragma unroll
    for (int ni = 0; ni < 2; ++ni) {
        int col = (nt0 + ni) * 16 + lm;
        float bv = b1f[col];
        #pragma unroll
        for (int r = 0; r < 4; ++r)
            out[(size_t)(nb + lg * 4 + r) * 128 + col] = __float2bfloat16(acc[ni][r] + bv);
    }
}

// FFN via MFMA: V2 = LN(V1 + gelu(V1@w1+b1)@w2+b2), 16 nodes/block.
__global__ __launch_bounds__(256, 2)
void ffn_mfma_kernel(const bf16* __restrict__ V1,
                     const bf16* __restrict__ w1p, const float* __restrict__ b1,
                     const bf16* __restrict__ w2p, const float* __restrict__ b2,
                     const float* __restrict__ g, const float* __restrict__ bta,
                     float* __restrict__ Vout)
{
    __shared__ __align__(16) bf16 sA[16][136];
    __shared__ __align__(16) bf16 sH[16][520];
    __shared__ float sX[16][132];
    const int nb  = blockIdx.x * 16;
    const int tid = threadIdx.x;
    const int lane = tid & 63, wid = tid >> 6;
    const int lm = lane & 15, lg = lane >> 4;
    {
        int c = tid;                    // 256 chunks of 8 bf16 = 16 rows x 128
        int r = c >> 4, off = (c & 15) * 8;
        *(uint4*)&sA[r][off] = *(const uint4*)(V1 + (size_t)(nb + r) * 128 + off);
    }
    __syncthreads();
    {
        f32x4 acc[8];
        #pragma unroll
        for (int i = 0; i < 8; ++i) acc[i] = (f32x4){0.f,0.f,0.f,0.f};
        do_gemm_1m<4, 32, 8>(&sA[0][0], 136, w1p, lane, wid * 8, acc);
        #pragma unroll
        for (int ni = 0; ni < 8; ++ni) {
            int col = (wid * 8 + ni) * 16 + lm;
            float bv = b1[col];
            #pragma unroll
            for (int r = 0; r < 4; ++r)
                sH[lg * 4 + r][col] = __float2bfloat16(gelu_f(acc[ni][r] + bv));
        }
    }
    __syncthreads();
    {
        f32x4 acc[2];
        acc[0] = (f32x4){0.f,0.f,0.f,0.f}; acc[1] = (f32x4){0.f,0.f,0.f,0.f};
        do_gemm_1m<16, 8, 2>(&sH[0][0], 520, w2p, lane, wid * 2, acc);
        #pragma unroll
        for (int ni = 0; ni < 2; ++ni) {
            int col = (wid * 2 + ni) * 16 + lm;
            float bv = b2[col];
            #pragma unroll
            for (int r = 0; r < 4; ++r) {
                int row = lg * 4 + r;
                sX[row][col] = __bfloat162float(sA[row][col]) + acc[ni][r] + bv;
            }
        }
    }
    __syncthreads();
    for (int n = wid; n < 16; n += 4) {
        float a = sX[n][lane], b = sX[n][lane + 64];
        float s = a + b, q = a * a + b * b;
        #pragma unroll
        for (int off = 32; off; off >>= 1) { s += __shfl_xor(s, off); q += __shfl_xor(q, off); }
        float mean = s * (1.f / 128.f);
        float var  = q * (1.f / 128.f) - mean * mean;
        float rs   = rsqrtf(var + 1e-5f);
        size_t base = (size_t)(nb + n) * 128;
        Vout[base + lane]      = (a - mean) * rs * g[lane]      + bta[lane];
        Vout[base + lane + 64] = (b - mean) * rs * g[lane + 64] + bta[lane + 64];
    }
}

// NODE message pass (validated rounds 5-13): occupancy-5, aliased LDS, Yvi buffer.
__global__ __launch_bounds__(256, 5)
void msg_node_kernel(const float* __restrict__ Vf,
                     const float* __restrict__ Ef,
                     const float* __restrict__ maskf,
                     const int*   __restrict__ Kidx,
                     const bf16*  __restrict__ Yvi,
                     const bf16* __restrict__ w1p,
                     const bf16* __restrict__ w2p, const float* __restrict__ b2f,
                     const bf16* __restrict__ w3p, const float* __restrict__ b3f,
                     const float* __restrict__ lng, const float* __restrict__ lnb,
                     const float* __restrict__ Vres,
                     bf16*  __restrict__ V1out)
{
    __shared__ __align__(16) char region0[26112];   // sA[0,25344) ; sH1[0,13056) ; sH2[13056,26112)
    __shared__ float sYvi[128];
    __shared__ float sMask[48];
    __shared__ float sS[128];

    bf16  (*sA)[264]  = reinterpret_cast<bf16(*)[264]>(region0);
    bf16  (*sH1)[136] = reinterpret_cast<bf16(*)[136]>(region0);
    bf16  (*sH2)[136] = reinterpret_cast<bf16(*)[136]>(region0 + 13056);

    const int node = blockIdx.x;
    const int tid  = threadIdx.x;
    const int lane = tid & 63;
    const int wid  = tid >> 6;
    const int z    = node >> 10;
    const int* krow = Kidx + node * KN;

    if (tid < 128) sYvi[tid] = __bfloat162float(Yvi[(size_t)node * 128 + tid]);
    if (tid >= 128 && tid < 128 + KN)
        sMask[tid - 128] = maskf[(size_t)node * KN + (tid - 128)];
    {
        const float* erow0 = Ef + (size_t)node * KN * 128;
        for (int c = tid; c < KN * 32; c += 256) {
            int r = c >> 5;
            int off = (c & 31) * 4;
            int kj = krow[r];
            float4 vj = *(const float4*)(Vf + ((size_t)(z * 1024 + kj)) * 128 + off);
            *(uint2*)&sA[r][off] = pack4(vj.x, vj.y, vj.z, vj.w);
            float4 ee = *(const float4*)(erow0 + r * 128 + off);
            *(uint2*)&sA[r][128 + off] = pack4(ee.x, ee.y, ee.z, ee.w);
        }
    }
    __syncthreads();                                   // B0: sA ready

    const int nt0 = wid * 2;
    const int lm  = lane & 15;
    const int lg  = lane >> 4;
    const f32x4 vzero = {0.f, 0.f, 0.f, 0.f};

    f32x4 acc[3][2];
    #pragma unroll
    for (int mt = 0; mt < 3; ++mt) { acc[mt][0] = vzero; acc[mt][1] = vzero; }
    do_gemm<4, 8>(&sA[0][0], 264, w1p, lane, nt0, acc);
    __syncthreads();                                   // B1: sA reads done (sH1 aliases sA)
    #pragma unroll
    for (int mt = 0; mt < 3; ++mt)
    #pragma unroll
    for (int ni = 0; ni < 2; ++ni) {
        int col = (nt0 + ni) * 16 + lm;
        float yv = sYvi[col];
        #pragma unroll
        for (int r = 0; r < 4; ++r) {
            int row = mt * 16 + lg * 4 + r;
            sH1[row][col] = __float2bfloat16(gelu_f(acc[mt][ni][r] + yv));
        }
    }
    __syncthreads();                                   // B2: sH1 ready

    #pragma unroll
    for (int mt = 0; mt < 3; ++mt) { acc[mt][0] = vzero; acc[mt][1] = vzero; }
    do_gemm<0, 4>(&sH1[0][0], 136, w2p, lane, nt0, acc);
    {
        float bc0 = b2f[nt0 * 16 + lm];
        float bc1 = b2f[(nt0 + 1) * 16 + lm];
        #pragma unroll
        for (int mt = 0; mt < 3; ++mt)
        #pragma unroll
        for (int r = 0; r < 4; ++r) {
            int row = mt * 16 + lg * 4 + r;
            sH2[row][nt0 * 16 + lm]       = __float2bfloat16(gelu_f(acc[mt][0][r] + bc0));
            sH2[row][(nt0 + 1) * 16 + lm] = __float2bfloat16(gelu_f(acc[mt][1][r] + bc1));
        }
    }
    __syncthreads();                                   // B3: sH2 ready

    #pragma unroll
    for (int mt = 0; mt < 3; ++mt) { acc[mt][0] = vzero; acc[mt][1] = vzero; }
    do_gemm<0, 4>(&sH2[0][0], 136, w3p, lane, nt0, acc);
    {
        float bc0 = b3f[nt0 * 16 + lm];
        float bc1 = b3f[(nt0 + 1) * 16 + lm];
        float cs0 = 0.f, cs1 = 0.f;
        #pragma unroll
        for (int mt = 0; mt < 3; ++mt)
        #pragma unroll
        for (int r = 0; r < 4; ++r) {
            float m = sMask[mt * 16 + lg * 4 + r];
            cs0 += (acc[mt][0][r] + bc0) * m;
            cs1 += (acc[mt][1][r] + bc1) * m;
        }
        cs0 += __shfl_xor(cs0, 16); cs0 += __shfl_xor(cs0, 32);
        cs1 += __shfl_xor(cs1, 16); cs1 += __shfl_xor(cs1, 32);
        if (lane < 16) {
            sS[nt0 * 16 + lane]       = cs0;
            sS[(nt0 + 1) * 16 + lane] = cs1;
        }
    }
    __syncthreads();                                   // B5: sS ready

    if (tid < 64) {
        float a = Vres[(size_t)node * 128 + tid]      + sS[tid];
        float b = Vres[(size_t)node * 128 + tid + 64] + sS[tid + 64];
        float s = a + b, q = a * a + b * b;
        #pragma unroll
        for (int off = 32; off; off >>= 1) { s += __shfl_xor(s, off); q += __shfl_xor(q, off); }
        float mean = s * (1.f / 128.f);
        float var  = q * (1.f / 128.f) - mean * mean;
        float rs   = rsqrtf(var + 1e-5f);
        V1out[(size_t)node * 128 + tid] =
            __float2bfloat16((a - mean) * rs * lng[tid] + lnb[tid]);
        V1out[(size_t)node * 128 + tid + 64] =
            __float2bfloat16((b - mean) * rs * lng[tid + 64] + lnb[tid + 64]);
    }
}

// EDGE MLP kernel with FUSED LN (validated R13): x in registers, sPart partials, direct E write.
__global__ __launch_bounds__(256, 5)
void mlp_edge_kernel(const float* __restrict__ Vf,     // V2 (f32) gather source
                     const float* __restrict__ Ef,
                     const float* __restrict__ maskf,
                     const int*   __restrict__ Kidx,
                     const bf16*  __restrict__ Yvi,    // YviE (bf16)
                     const bf16* __restrict__ w1p,
                     const bf16* __restrict__ w2p, const float* __restrict__ b2f,
                     const bf16* __restrict__ w3p, const float* __restrict__ b3f,
                     const float* __restrict__ lng, const float* __restrict__ lnb,
                     float* __restrict__ Eout)         // f32 final E
{
    __shared__ __align__(16) char region0[26112];
    __shared__ float sYvi[128];
    __shared__ float sMask[48];
    __shared__ float sPart[48][4][2];                  // per-row {sum, sumsq} per wave

    bf16  (*sA)[264]  = reinterpret_cast<bf16(*)[264]>(region0);
    bf16  (*sH1)[136] = reinterpret_cast<bf16(*)[136]>(region0);
    bf16  (*sH2)[136] = reinterpret_cast<bf16(*)[136]>(region0 + 13056);

    const int node = blockIdx.x;
    const int tid  = threadIdx.x;
    const int lane = tid & 63;
    const int wid  = tid >> 6;
    const int z    = node >> 10;
    const int* krow = Kidx + node * KN;

    if (tid < 128) sYvi[tid] = __bfloat162float(Yvi[(size_t)node * 128 + tid]);
    if (tid >= 128 && tid < 128 + KN)
        sMask[tid - 128] = maskf[(size_t)node * KN + (tid - 128)];
    {
        const float* erow0 = Ef + (size_t)node * KN * 128;
        for (int c = tid; c < KN * 32; c += 256) {
            int r = c >> 5;
            int off = (c & 31) * 4;
            int kj = krow[r];
            float4 vj = *(const float4*)(Vf + ((size_t)(z * 1024 + kj)) * 128 + off);
            *(uint2*)&sA[r][off] = pack4(vj.x, vj.y, vj.z, vj.w);
            float4 ee = *(const float4*)(erow0 + r * 128 + off);
            *(uint2*)&sA[r][128 + off] = pack4(ee.x, ee.y, ee.z, ee.w);
        }
    }
    __syncthreads();                                   // B0

    const int nt0 = wid * 2;
    const int lm  = lane & 15;
    const int lg  = lane >> 4;
    const f32x4 vzero = {0.f, 0.f, 0.f, 0.f};

    f32x4 acc[3][2];
    #pragma unroll
    for (int mt = 0; mt < 3; ++mt) { acc[mt][0] = vzero; acc[mt][1] = vzero; }
    do_gemm<4, 8>(&sA[0][0], 264, w1p, lane, nt0, acc);
    __syncthreads();                                   // B1
    #pragma unroll
    for (int mt = 0; mt < 3; ++mt)
    #pragma unroll
    for (int ni = 0; ni < 2; ++ni) {
        int col = (nt0 + ni) * 16 + lm;
        float yv = sYvi[col];
        #pragma unroll
        for (int r = 0; r < 4; ++r) {
            int row = mt * 16 + lg * 4 + r;
            sH1[row][col] = __float2bfloat16(gelu_f(acc[mt][ni][r] + yv));
        }
    }
    __syncthreads();                                   // B2

    #pragma unroll
    for (int mt = 0; mt < 3; ++mt) { acc[mt][0] = vzero; acc[mt][1] = vzero; }
    do_gemm<0, 4>(&sH1[0][0], 136, w2p, lane, nt0, acc);
    {
        float bc0 = b2f[nt0 * 16 + lm];
        float bc1 = b2f[(nt0 + 1) * 16 + lm];
        #pragma unroll
        for (int mt = 0; mt < 3; ++mt)
        #pragma unroll
        for (int r = 0; r < 4; ++r) {
            int row = mt * 16 + lg * 4 + r;
            sH2[row][nt0 * 16 + lm]       = __float2bfloat16(gelu_f(acc[mt][0][r] + bc0));
            sH2[row][(nt0 + 1) * 16 + lm] = __float2bfloat16(gelu_f(acc[mt][1][r] + bc1));
        }
    }
    __syncthreads();                                   // B3

    #pragma unroll
    for (int mt = 0; mt < 3; ++mt) { acc[mt][0] = vzero; acc[mt][1] = vzero; }
    do_gemm<0, 4>(&sH2[0][0], 136, w3p, lane, nt0, acc);

    // ---- fused epilogue: x = E + Me*mask (registers), per-row partial sums to sPart ----
    float xv[3][4][2];
    {
        float bc0 = b3f[nt0 * 16 + lm];
        float bc1 = b3f[(nt0 + 1) * 16 + lm];
        const float* erow0 = Ef + (size_t)node * KN * 128;
        #pragma unroll
        for (int mt = 0; mt < 3; ++mt)
        #pragma unroll
        for (int r = 0; r < 4; ++r) {
            int row = mt * 16 + lg * 4 + r;
            float m = sMask[row];
            float x0 = erow0[row * 128 + nt0 * 16 + lm]       + (acc[mt][0][r] + bc0) * m;
            float x1 = erow0[row * 128 + (nt0 + 1) * 16 + lm] + (acc[mt][1][r] + bc1) * m;
            xv[mt][r][0] = x0; xv[mt][r][1] = x1;
            float s = x0 + x1, q = x0 * x0 + x1 * x1;
            s += __shfl_xor(s, 1); q += __shfl_xor(q, 1);
            s += __shfl_xor(s, 2); q += __shfl_xor(q, 2);
            s += __shfl_xor(s, 4); q += __shfl_xor(q, 4);
            s += __shfl_xor(s, 8); q += __shfl_xor(q, 8);
            if (lm == 0) { sPart[row][wid][0] = s; sPart[row][wid][1] = q; }
        }
    }
    __syncthreads();                                   // B4: sPart ready

    {
        float g0 = lng[nt0 * 16 + lm],       b0 = lnb[nt0 * 16 + lm];
        float g1 = lng[(nt0 + 1) * 16 + lm], b1 = lnb[(nt0 + 1) * 16 + lm];
        float* orow0 = Eout + (size_t)node * KN * 128;
        #pragma unroll
        for (int mt = 0; mt < 3; ++mt)
        #pragma unroll
        for (int r = 0; r < 4; ++r) {
            int row = mt * 16 + lg * 4 + r;
            float s = sPart[row][0][0] + sPart[row][1][0] + sPart[row][2][0] + sPart[row][3][0];
            float q = sPart[row][0][1] + sPart[row][1][1] + sPart[row][2][1] + sPart[row][3][1];
            float mean = s * (1.f / 128.f);
            float var  = q * (1.f / 128.f) - mean * mean;
            float rs   = rsqrtf(var + 1e-5f);
            orow0[row * 128 + nt0 * 16 + lm]       = (xv[mt][r][0] - mean) * rs * g0 + b0;
            orow0[row * 128 + (nt0 + 1) * 16 + lm] = (xv[mt][r][1] - mean) * rs * g1 + b1;
        }
    }
}

extern "C" void kernel_launch(void* const* d_in, const int* in_sizes, int n_in,
                              void* d_out, int out_size, void* d_ws, size_t ws_size,
                              hipStream_t stream) {
    const float* V     = (const float*)d_in[0];
    const float* E     = (const float*)d_in[1];
    const float* emask = (const float*)d_in[2];
    const float* nm_w1 = (const float*)d_in[3];
    const float* nm_b1 = (const float*)d_in[4];
    const float* nm_w2 = (const float*)d_in[5];
    const float* nm_b2 = (const float*)d_in[6];
    const float* nm_w3 = (const float*)d_in[7];
    const float* nm_b3 = (const float*)d_in[8];
    const float* nmn_g = (const float*)d_in[9];
    const float* nmn_b = (const float*)d_in[10];
    const float* ffn_w1 = (const float*)d_in[11];
    const float* ffn_b1 = (const float*)d_in[12];
    const float* ffn_w2 = (const float*)d_in[13];
    const float* ffn_b2 = (const float*)d_in[14];
    const float* fn_g  = (const float*)d_in[15];
    const float* fn_b  = (const float*)d_in[16];
    const float* em_w1 = (const float*)d_in[17];
    const float* em_b1 = (const float*)d_in[18];
    const float* em_w2 = (const float*)d_in[19];
    const float* em_b2 = (const float*)d_in[20];
    const float* em_w3 = (const float*)d_in[21];
    const float* em_b3 = (const float*)d_in[22];
    const float* emn_g = (const float*)d_in[23];
    const float* emn_b = (const float*)d_in[24];
    const int*  K     = (const int*)d_in[25];

    // ws layout (proven footprint):
    //   [0, 327680)            packed msg weights (bf16, 6 segments)
    //   [327680, +1MB)         V1f (bf16) -- reused as YviE after ffn
    //   [327680+1MB, +2MB)     YviN (bf16)
    char* ws = (char*)d_ws;
    bf16* Pall    = (bf16*)(ws);
    bf16* p_nm_w1 = (bf16*)(ws);
    bf16* p_nm_w2 = (bf16*)(ws + 98304);
    bf16* p_nm_w3 = (bf16*)(ws + 131072);
    bf16* p_em_w1 = (bf16*)(ws + 163840);
    bf16* p_em_w2 = (bf16*)(ws + 262144);
    bf16* p_em_w3 = (bf16*)(ws + 294912);
    bf16* V1f  = (bf16*)(ws + 327680);
    bf16* YviE = (bf16*)(ws + 327680);             // reuses V1f slot (dead after ffn)
    bf16* YviN = (bf16*)(ws + 327680 + 1048576);

    float* V2out = (float*)d_out;                 // [4,1024,128] f32
    float* Eout  = (float*)d_out + 524288;        // [4,1024,48,128] f32

    // ffn packed weights staged in the TAIL of Eout: written by pack_ffn, read by
    // ffn_mfma, then overwritten by mlp_edge's final-E write.
    bf16* fw1p = (bf16*)((float*)d_out + 25690112 - 65536);
    bf16* fw2p = (bf16*)((float*)d_out + 25690112 - 32768);

    pack_all_kernel<<<640, 256, 0, stream>>>(nm_w1, nm_w2, nm_w3, em_w1, em_w2, em_w3, Pall);
    pack_ffn_kernel<<<512, 256, 0, stream>>>(ffn_w1, ffn_w2, fw1p, fw2p);

    yvi_mfma_kernel<<<ZN / 16, 256, 0, stream>>>(V, p_nm_w1, nm_b1, YviN);

    msg_node_kernel<<<ZN, 256, 0, stream>>>(
        V, E, emask, K, YviN,
        p_nm_w1, p_nm_w2, nm_b2, p_nm_w3, nm_b3,
        nmn_g, nmn_b, V, V1f);

    ffn_mfma_kernel<<<ZN / 16, 256, 0, stream>>>(
        V1f, fw1p, ffn_b1, fw2p, ffn_b2, fn_g, fn_b, V2out);

    yvi_mfma_kernel<<<ZN / 16, 256, 0, stream>>>(V2out, p_em_w1, em_b1, YviE);

    mlp_edge_kernel<<<ZN, 256, 0, stream>>>(
        V2out, E, emask, K, YviE,
        p_em_w1, p_em_w2, em_b2, p_em_w3, em_b3,
        emn_g, emn_b, Eout);
}